// Round 1
// baseline (2201.815 us; speedup 1.0000x reference)
//
#include <hip/hip_runtime.h>
#include <hip/hip_bf16.h>

#define N_NODES 100000
#define N_EDGES 1600000
#define F_IN    700
#define HDIM    128
#define SCAN_B  256
#define NB_SCAN ((N_NODES + SCAN_B - 1) / SCAN_B)   // 391

// ---------------------------------------------------------------- CSR build
__global__ void count_edges(const int* __restrict__ graph, int* __restrict__ cnt) {
    int e = blockIdx.x * blockDim.x + threadIdx.x;
    if (e < N_EDGES) {
        int dst = graph[2 * e + 1];
        atomicAdd(&cnt[dst], 1);
    }
}

__global__ void scan1(const int* __restrict__ cnt, int* __restrict__ incl,
                      int* __restrict__ blk) {
    __shared__ int s[SCAN_B];
    int tid = threadIdx.x;
    int i = blockIdx.x * SCAN_B + tid;
    s[tid] = (i < N_NODES) ? cnt[i] : 0;
    __syncthreads();
    for (int off = 1; off < SCAN_B; off <<= 1) {
        int t = (tid >= off) ? s[tid - off] : 0;
        __syncthreads();
        s[tid] += t;
        __syncthreads();
    }
    if (i < N_NODES) incl[i] = s[tid];
    if (tid == SCAN_B - 1) blk[blockIdx.x] = s[tid];
}

__global__ void scan2(const int* __restrict__ blk, int* __restrict__ blkoff) {
    __shared__ int s[512];
    int tid = threadIdx.x;
    s[tid] = (tid < NB_SCAN) ? blk[tid] : 0;
    __syncthreads();
    for (int off = 1; off < 512; off <<= 1) {
        int t = (tid >= off) ? s[tid - off] : 0;
        __syncthreads();
        s[tid] += t;
        __syncthreads();
    }
    if (tid < NB_SCAN) blkoff[tid] = (tid == 0) ? 0 : s[tid - 1];
}

__global__ void scan3(const int* __restrict__ incl, const int* __restrict__ blkoff,
                      int* __restrict__ row_ptr) {
    int i = blockIdx.x * SCAN_B + threadIdx.x;
    if (i < N_NODES) {
        row_ptr[i + 1] = incl[i] + blkoff[i >> 8];
        if (i == 0) row_ptr[0] = 0;
    }
}

__global__ void fill_edges(const int* __restrict__ graph, const int* __restrict__ row_ptr,
                           int* __restrict__ cursor, int* __restrict__ esrc) {
    int e = blockIdx.x * blockDim.x + threadIdx.x;
    if (e < N_EDGES) {
        int src = graph[2 * e];
        int dst = graph[2 * e + 1];
        int pos = row_ptr[dst] + atomicAdd(&cursor[dst], 1);
        esrc[pos] = src;
    }
}

// ------------------------------------------------------- fused dual GEMM
// Cn = A @ Bn ; Cs = A @ Bs + bias.  A: MxK row-major, Bn/Bs: Kx128, C: Mx128.
#define BM 64
#define BKK 16
__global__ __launch_bounds__(256) void dual_gemm(
    const float* __restrict__ A, int M, int K,
    const float* __restrict__ Bn, const float* __restrict__ Bs,
    const float* __restrict__ bias,
    float* __restrict__ Cn, float* __restrict__ Cs) {
    __shared__ float As[BM][BKK + 1];
    __shared__ float Bns[BKK][HDIM];
    __shared__ float Bss[BKK][HDIM];

    int tid = threadIdx.x;
    int tx = tid & 31;   // col group -> cols tx*4 .. +4
    int ty = tid >> 5;   // row group -> rows ty*8 .. +8
    int row0 = blockIdx.x * BM;

    float accn[8][4] = {};
    float accs[8][4] = {};

    int ar = tid >> 2;          // 0..63 : A row within tile
    int ak = (tid & 3) * 4;     // 0,4,8,12 : k offset
    int bk = tid >> 4;          // 0..15 : B k-row
    int bc = (tid & 15) * 8;    // 0..120 : B col

    for (int k0 = 0; k0 < K; k0 += BKK) {
        int grow = row0 + ar;
        #pragma unroll
        for (int t = 0; t < 4; t++) {
            int gk = k0 + ak + t;
            As[ar][ak + t] = (grow < M && gk < K) ? A[grow * K + gk] : 0.0f;
        }
        int gk = k0 + bk;
        if (gk < K) {
            float4 v0 = *(const float4*)&Bn[gk * HDIM + bc];
            float4 v1 = *(const float4*)&Bn[gk * HDIM + bc + 4];
            float4 w0 = *(const float4*)&Bs[gk * HDIM + bc];
            float4 w1 = *(const float4*)&Bs[gk * HDIM + bc + 4];
            *(float4*)&Bns[bk][bc]     = v0;
            *(float4*)&Bns[bk][bc + 4] = v1;
            *(float4*)&Bss[bk][bc]     = w0;
            *(float4*)&Bss[bk][bc + 4] = w1;
        } else {
            float4 z = {0.f, 0.f, 0.f, 0.f};
            *(float4*)&Bns[bk][bc]     = z;
            *(float4*)&Bns[bk][bc + 4] = z;
            *(float4*)&Bss[bk][bc]     = z;
            *(float4*)&Bss[bk][bc + 4] = z;
        }
        __syncthreads();

        #pragma unroll
        for (int kk = 0; kk < BKK; kk++) {
            float a[8];
            #pragma unroll
            for (int i = 0; i < 8; i++) a[i] = As[ty * 8 + i][kk];
            float4 bn4 = *(const float4*)&Bns[kk][tx * 4];
            float4 bs4 = *(const float4*)&Bss[kk][tx * 4];
            #pragma unroll
            for (int i = 0; i < 8; i++) {
                accn[i][0] += a[i] * bn4.x; accn[i][1] += a[i] * bn4.y;
                accn[i][2] += a[i] * bn4.z; accn[i][3] += a[i] * bn4.w;
                accs[i][0] += a[i] * bs4.x; accs[i][1] += a[i] * bs4.y;
                accs[i][2] += a[i] * bs4.z; accs[i][3] += a[i] * bs4.w;
            }
        }
        __syncthreads();
    }

    float4 bb = *(const float4*)&bias[tx * 4];
    #pragma unroll
    for (int i = 0; i < 8; i++) {
        int r = row0 + ty * 8 + i;
        if (r < M) {
            float4 vn = {accn[i][0], accn[i][1], accn[i][2], accn[i][3]};
            float4 vs = {accs[i][0] + bb.x, accs[i][1] + bb.y,
                         accs[i][2] + bb.z, accs[i][3] + bb.w};
            *(float4*)&Cn[r * HDIM + tx * 4] = vn;
            *(float4*)&Cs[r * HDIM + tx * 4] = vs;
        }
    }
}

// ------------------------------------------------------------- aggregation
// pre[n,:] += (sum over incoming edges of hn[src,:]) / max(deg,1)
__global__ void aggregate(const float* __restrict__ hn, const int* __restrict__ row_ptr,
                          const int* __restrict__ esrc, float* __restrict__ pre) {
    int n = blockIdx.x;
    int c = threadIdx.x;  // 128 channels
    int start = row_ptr[n], end = row_ptr[n + 1];
    int deg = end - start;
    __shared__ int ls[128];
    float acc = 0.0f;
    for (int base = start; base < end; base += 128) {
        int cnt = min(end - base, 128);
        __syncthreads();
        if (c < cnt) ls[c] = esrc[base + c];
        __syncthreads();
        int j = 0;
        for (; j + 4 <= cnt; j += 4) {
            float v0 = hn[ls[j] * HDIM + c];
            float v1 = hn[ls[j + 1] * HDIM + c];
            float v2 = hn[ls[j + 2] * HDIM + c];
            float v3 = hn[ls[j + 3] * HDIM + c];
            acc += (v0 + v1) + (v2 + v3);
        }
        for (; j < cnt; ++j) acc += hn[ls[j] * HDIM + c];
    }
    float denom = (float)max(deg, 1);
    pre[n * HDIM + c] += acc / denom;
}

// --------------------------------------------------------------- batch norm
__global__ void bn_stats(const float* __restrict__ P, float* __restrict__ gsum,
                         float* __restrict__ gsumsq, int M, int C) {
    int tid = threadIdx.x;
    int c = tid % C;
    int rpb = 256 / C;
    float s = 0.0f, s2 = 0.0f;
    for (int r = blockIdx.x * rpb + tid / C; r < M; r += gridDim.x * rpb) {
        float v = P[r * C + c];
        s += v;
        s2 += v * v;
    }
    __shared__ float ss[256], ss2[256];
    ss[tid] = s; ss2[tid] = s2;
    __syncthreads();
    for (int off = 128; off >= C; off >>= 1) {
        if (tid < off) { ss[tid] += ss[tid + off]; ss2[tid] += ss2[tid + off]; }
        __syncthreads();
    }
    if (tid < C) {
        atomicAdd(&gsum[tid], ss[tid]);
        atomicAdd(&gsumsq[tid], ss2[tid]);
    }
}

__global__ void bn_finalize(const float* __restrict__ gsum, const float* __restrict__ gsumsq,
                            const float* __restrict__ gamma, const float* __restrict__ beta,
                            float* __restrict__ scale, float* __restrict__ shift,
                            int M, int C) {
    int c = threadIdx.x;
    if (c < C) {
        float mean = gsum[c] / (float)M;
        float var = gsumsq[c] / (float)M - mean * mean;
        float rstd = rsqrtf(var + 1e-5f);
        float sc = rstd * gamma[c];
        scale[c] = sc;
        shift[c] = beta[c] - mean * sc;
    }
}

// out = relu(P*scale+shift [+ res]) ; elementwise, float4 over rows of C cols
__global__ void bn_apply(const float* __restrict__ P, const float* __restrict__ res,
                         float* __restrict__ out, const float* __restrict__ scale,
                         const float* __restrict__ shift, int total4, int Cdiv4) {
    for (int f = blockIdx.x * blockDim.x + threadIdx.x; f < total4;
         f += gridDim.x * blockDim.x) {
        int c4 = (f % Cdiv4) * 4;
        float4 v = ((const float4*)P)[f];
        v.x = v.x * scale[c4 + 0] + shift[c4 + 0];
        v.y = v.y * scale[c4 + 1] + shift[c4 + 1];
        v.z = v.z * scale[c4 + 2] + shift[c4 + 2];
        v.w = v.w * scale[c4 + 3] + shift[c4 + 3];
        if (res) {
            float4 rv = ((const float4*)res)[f];
            v.x += rv.x; v.y += rv.y; v.z += rv.z; v.w += rv.w;
        }
        v.x = fmaxf(v.x, 0.0f); v.y = fmaxf(v.y, 0.0f);
        v.z = fmaxf(v.z, 0.0f); v.w = fmaxf(v.w, 0.0f);
        ((float4*)out)[f] = v;
    }
}

// --------------------------------------------------------------- MLP head
// Z = H(Mx128) @ W1(128x64) + b1
__global__ __launch_bounds__(256) void mlp_gemm(const float* __restrict__ H,
                                                const float* __restrict__ W1,
                                                const float* __restrict__ b1,
                                                float* __restrict__ Z, int M) {
    __shared__ float hs[64 * 132];
    __shared__ float ws[128 * 64];
    int tid = threadIdx.x;
    int tx = tid & 15;   // cols tx*4 .. +4
    int ty = tid >> 4;   // rows ty*4 .. +4
    int row0 = blockIdx.x * 64;

    #pragma unroll
    for (int t = 0; t < 8; t++) {           // W1: 2048 float4 / 256 thr
        int f = tid + t * 256;
        int r = f >> 4, c4 = (f & 15) * 4;
        *(float4*)&ws[r * 64 + c4] = *(const float4*)&W1[r * 64 + c4];
    }
    #pragma unroll
    for (int t = 0; t < 8; t++) {           // H tile: 64x128 = 2048 float4
        int f = tid + t * 256;
        int r = f >> 5, c4 = (f & 31) * 4;
        int gr = row0 + r;
        float4 v = {0.f, 0.f, 0.f, 0.f};
        if (gr < M) v = *(const float4*)&H[gr * HDIM + c4];
        *(float4*)&hs[r * 132 + c4] = v;
    }
    __syncthreads();

    float acc[4][4] = {};
    for (int k = 0; k < 128; k++) {
        float a[4];
        #pragma unroll
        for (int i = 0; i < 4; i++) a[i] = hs[(ty * 4 + i) * 132 + k];
        float4 b4 = *(const float4*)&ws[k * 64 + tx * 4];
        #pragma unroll
        for (int i = 0; i < 4; i++) {
            acc[i][0] += a[i] * b4.x; acc[i][1] += a[i] * b4.y;
            acc[i][2] += a[i] * b4.z; acc[i][3] += a[i] * b4.w;
        }
    }
    float4 bb = *(const float4*)&b1[tx * 4];
    #pragma unroll
    for (int i = 0; i < 4; i++) {
        int r = row0 + ty * 4 + i;
        if (r < M) {
            float4 v = {acc[i][0] + bb.x, acc[i][1] + bb.y,
                        acc[i][2] + bb.z, acc[i][3] + bb.w};
            *(float4*)&Z[r * 64 + tx * 4] = v;
        }
    }
}

// out[n] = dot(Z[n,:], W2) + b2   (one wave per node)
__global__ void final_out(const float* __restrict__ Z, const float* __restrict__ W2,
                          const float* __restrict__ b2, float* __restrict__ out) {
    int t = blockIdx.x * blockDim.x + threadIdx.x;
    int n = t >> 6;
    int lane = t & 63;
    if (n >= N_NODES) return;
    float v = Z[n * 64 + lane] * W2[lane];
    #pragma unroll
    for (int off = 32; off >= 1; off >>= 1) v += __shfl_down(v, off, 64);
    if (lane == 0) out[n] = v + b2[0];
}

// ------------------------------------------------------------------ driver
extern "C" void kernel_launch(void* const* d_in, const int* in_sizes, int n_in,
                              void* d_out, int out_size, void* d_ws, size_t ws_size,
                              hipStream_t stream) {
    const float* X       = (const float*)d_in[0];
    const int*   graph   = (const int*)d_in[1];
    const float* Wself0  = (const float*)d_in[2];
    const float* Wneigh0 = (const float*)d_in[3];
    const float* b0      = (const float*)d_in[4];
    const float* Wself   = (const float*)d_in[5];
    const float* Wneigh  = (const float*)d_in[6];
    const float* bvec    = (const float*)d_in[7];
    const float* bn_g    = (const float*)d_in[8];
    const float* bn_b    = (const float*)d_in[9];
    const float* W1      = (const float*)d_in[10];
    const float* b1      = (const float*)d_in[11];
    const float* bng1    = (const float*)d_in[12];
    const float* bnb1    = (const float*)d_in[13];
    const float* W2      = (const float*)d_in[14];
    const float* b2      = (const float*)d_in[15];
    float* out = (float*)d_out;

    size_t off = 0;
    auto alloc = [&](size_t bytes) {
        void* p = (char*)d_ws + off;
        off += (bytes + 255) & ~(size_t)255;
        return p;
    };
    int* cnt     = (int*)alloc(N_NODES * 4);
    int* cursor  = (int*)alloc(N_NODES * 4);
    int* row_ptr = (int*)alloc((N_NODES + 1) * 4);
    int* incl    = (int*)alloc(N_NODES * 4);
    int* blk     = (int*)alloc(NB_SCAN * 4);
    int* blkoff  = (int*)alloc(NB_SCAN * 4);
    int* esrc    = (int*)alloc((size_t)N_EDGES * 4);
    float* B0    = (float*)alloc((size_t)N_NODES * HDIM * 4);
    float* B1    = (float*)alloc((size_t)N_NODES * HDIM * 4);
    float* B2    = (float*)alloc((size_t)N_NODES * HDIM * 4);
    float* Z     = (float*)alloc((size_t)N_NODES * 64 * 4);
    float* stats = (float*)alloc(512 * 4);  // gsum[128] gsumsq[128] scale[128] shift[128]
    float* gsum = stats, *gsumsq = stats + 128, *scale = stats + 256, *shift = stats + 384;

    const int EB = (N_EDGES + 255) / 256;
    const int GB = (N_NODES + BM - 1) / BM;

    // CSR build
    hipMemsetAsync(cnt, 0, N_NODES * 4, stream);
    hipMemsetAsync(cursor, 0, N_NODES * 4, stream);
    count_edges<<<EB, 256, 0, stream>>>(graph, cnt);
    scan1<<<NB_SCAN, SCAN_B, 0, stream>>>(cnt, incl, blk);
    scan2<<<1, 512, 0, stream>>>(blk, blkoff);
    scan3<<<NB_SCAN, SCAN_B, 0, stream>>>(incl, blkoff, row_ptr);
    fill_edges<<<EB, 256, 0, stream>>>(graph, row_ptr, cursor, esrc);

    float* h   = B0;
    float* hn  = B1;
    float* pre = B2;

    // ---- layer 0 (K = 700)
    dual_gemm<<<GB, 256, 0, stream>>>(X, N_NODES, F_IN, Wneigh0, Wself0, b0, hn, pre);
    aggregate<<<N_NODES, 128, 0, stream>>>(hn, row_ptr, esrc, pre);
    hipMemsetAsync(stats, 0, 256 * 4, stream);
    bn_stats<<<512, 256, 0, stream>>>(pre, gsum, gsumsq, N_NODES, 128);
    bn_finalize<<<1, 128, 0, stream>>>(gsum, gsumsq, bn_g, bn_b, scale, shift, N_NODES, 128);
    bn_apply<<<1024, 256, 0, stream>>>(pre, nullptr, h, scale, shift,
                                       N_NODES * HDIM / 4, HDIM / 4);

    // ---- layers 1..3 (K = 128, residual)
    for (int l = 0; l < 3; l++) {
        dual_gemm<<<GB, 256, 0, stream>>>(h, N_NODES, HDIM,
                                          Wneigh + l * HDIM * HDIM,
                                          Wself + l * HDIM * HDIM,
                                          bvec + l * HDIM, hn, pre);
        aggregate<<<N_NODES, 128, 0, stream>>>(hn, row_ptr, esrc, pre);
        hipMemsetAsync(stats, 0, 256 * 4, stream);
        bn_stats<<<512, 256, 0, stream>>>(pre, gsum, gsumsq, N_NODES, 128);
        bn_finalize<<<1, 128, 0, stream>>>(gsum, gsumsq, bn_g + (l + 1) * HDIM,
                                           bn_b + (l + 1) * HDIM, scale, shift,
                                           N_NODES, 128);
        bn_apply<<<1024, 256, 0, stream>>>(pre, h, pre, scale, shift,
                                           N_NODES * HDIM / 4, HDIM / 4);
        float* t = h; h = pre; pre = t;   // new h is old pre
    }

    // ---- MLP head
    mlp_gemm<<<GB, 256, 0, stream>>>(h, W1, b1, Z, N_NODES);
    hipMemsetAsync(stats, 0, 256 * 4, stream);
    bn_stats<<<512, 256, 0, stream>>>(Z, gsum, gsumsq, N_NODES, 64);
    bn_finalize<<<1, 64, 0, stream>>>(gsum, gsumsq, bng1, bnb1, scale, shift, N_NODES, 64);
    bn_apply<<<1024, 256, 0, stream>>>(Z, nullptr, Z, scale, shift,
                                       N_NODES * 64 / 4, 64 / 4);
    final_out<<<(N_NODES * 64) / 256, 256, 0, stream>>>(Z, W2, b2, out);
}

// Round 2
// 1877.452 us; speedup vs baseline: 1.1728x; 1.1728x over previous
//
#include <hip/hip_runtime.h>
#include <hip/hip_bf16.h>

#define N_NODES 100000
#define N_EDGES 1600000
#define F_IN    700
#define KPAD0   704
#define HDIM    128
#define SCAN_B  256
#define NB_SCAN ((N_NODES + SCAN_B - 1) / SCAN_B)   // 391

typedef _Float16 half8 __attribute__((ext_vector_type(8)));
typedef float floatx4 __attribute__((ext_vector_type(4)));

// ---------------------------------------------------------------- CSR build
__global__ void count_edges(const int* __restrict__ graph, int* __restrict__ cnt) {
    int e = blockIdx.x * blockDim.x + threadIdx.x;
    if (e < N_EDGES) {
        int dst = graph[2 * e + 1];
        atomicAdd(&cnt[dst], 1);
    }
}

__global__ void scan1(const int* __restrict__ cnt, int* __restrict__ incl,
                      int* __restrict__ blk) {
    __shared__ int s[SCAN_B];
    int tid = threadIdx.x;
    int i = blockIdx.x * SCAN_B + tid;
    s[tid] = (i < N_NODES) ? cnt[i] : 0;
    __syncthreads();
    for (int off = 1; off < SCAN_B; off <<= 1) {
        int t = (tid >= off) ? s[tid - off] : 0;
        __syncthreads();
        s[tid] += t;
        __syncthreads();
    }
    if (i < N_NODES) incl[i] = s[tid];
    if (tid == SCAN_B - 1) blk[blockIdx.x] = s[tid];
}

__global__ void scan2(const int* __restrict__ blk, int* __restrict__ blkoff) {
    __shared__ int s[512];
    int tid = threadIdx.x;
    s[tid] = (tid < NB_SCAN) ? blk[tid] : 0;
    __syncthreads();
    for (int off = 1; off < 512; off <<= 1) {
        int t = (tid >= off) ? s[tid - off] : 0;
        __syncthreads();
        s[tid] += t;
        __syncthreads();
    }
    if (tid < NB_SCAN) blkoff[tid] = (tid == 0) ? 0 : s[tid - 1];
}

__global__ void scan3(const int* __restrict__ incl, const int* __restrict__ blkoff,
                      int* __restrict__ row_ptr) {
    int i = blockIdx.x * SCAN_B + threadIdx.x;
    if (i < N_NODES) {
        row_ptr[i + 1] = incl[i] + blkoff[i >> 8];
        if (i == 0) row_ptr[0] = 0;
    }
}

__global__ void fill_edges(const int* __restrict__ graph, const int* __restrict__ row_ptr,
                           int* __restrict__ cursor, int* __restrict__ esrc) {
    int e = blockIdx.x * blockDim.x + threadIdx.x;
    if (e < N_EDGES) {
        int src = graph[2 * e];
        int dst = graph[2 * e + 1];
        int pos = row_ptr[dst] + atomicAdd(&cursor[dst], 1);
        esrc[pos] = src;
    }
}

// ---------------------------------------------- weight transpose+pack (fp16)
// layer0: Wn(700x128), Ws(700x128) -> Wt (256 x 704): Wt[n][k]=Wn[k][n] (n<128)
__global__ void build_wt0(const float* __restrict__ Wn, const float* __restrict__ Ws,
                          _Float16* __restrict__ Wt) {
    int idx = blockIdx.x * blockDim.x + threadIdx.x;
    if (idx >= 256 * KPAD0) return;
    int n = idx / KPAD0, k = idx % KPAD0;
    float v = 0.0f;
    if (k < F_IN) v = (n < 128) ? Wn[k * 128 + n] : Ws[k * 128 + (n - 128)];
    Wt[idx] = (_Float16)v;
}

// layers 1..3: Wneigh(3,128,128), Wself(3,128,128) -> Wtl (3 x 256 x 128)
__global__ void build_wtl(const float* __restrict__ Wn, const float* __restrict__ Ws,
                          _Float16* __restrict__ Wt) {
    int idx = blockIdx.x * blockDim.x + threadIdx.x;
    if (idx >= 3 * 256 * 128) return;
    int l = idx / (256 * 128);
    int rem = idx % (256 * 128);
    int n = rem / 128, k = rem % 128;
    float v = (n < 128) ? Wn[l * 16384 + k * 128 + n]
                        : Ws[l * 16384 + k * 128 + (n - 128)];
    Wt[idx] = (_Float16)v;
}

// ------------------------------------------------------- fused dual MFMA GEMM
// Cn = A @ Wt[0:128]^T ; Cs = A @ Wt[128:256]^T + bias
// A: MxK fp32 row-major (converted to fp16 in staging). Wt: 256 x Kpad fp16.
#define GBM 128
#define GBK 32
#define LDA 40   // LDS leading dim in halves (pad: 2-way conflict max = free)
__global__ __launch_bounds__(256) void dual_gemm_mfma(
    const float* __restrict__ A, int M, int K, int Kpad,
    const _Float16* __restrict__ Wt, const float* __restrict__ bias,
    float* __restrict__ Cn, float* __restrict__ Cs) {
    __shared__ _Float16 As[GBM][LDA];
    __shared__ _Float16 Bt[256][LDA];

    int tid = threadIdx.x;
    int wave = tid >> 6, lane = tid & 63;
    int lm = lane & 15, quad = lane >> 4;
    int wm = wave >> 1, wn = wave & 1;      // 2x2 wave grid: 64 rows x 128 cols each
    int row0 = blockIdx.x * GBM;

    floatx4 acc[4][8] = {};

    for (int k0 = 0; k0 < Kpad; k0 += GBK) {
        // stage A (convert fp32->fp16): 128x32 halves = 512 chunks of 8
        #pragma unroll
        for (int tt = 0; tt < 2; tt++) {
            int f = tid + tt * 256;
            int r = f >> 2, c = (f & 3) * 8;
            int grow = row0 + r;
            int gk = k0 + c;
            half8 h;
            if (grow < M && gk + 8 <= K) {
                const float* p = &A[(size_t)grow * K + gk];
                float2 v0 = *(const float2*)(p + 0);
                float2 v1 = *(const float2*)(p + 2);
                float2 v2 = *(const float2*)(p + 4);
                float2 v3 = *(const float2*)(p + 6);
                h[0] = (_Float16)v0.x; h[1] = (_Float16)v0.y;
                h[2] = (_Float16)v1.x; h[3] = (_Float16)v1.y;
                h[4] = (_Float16)v2.x; h[5] = (_Float16)v2.y;
                h[6] = (_Float16)v3.x; h[7] = (_Float16)v3.y;
            } else {
                #pragma unroll
                for (int i = 0; i < 8; i++)
                    h[i] = (grow < M && gk + i < K)
                               ? (_Float16)A[(size_t)grow * K + gk + i] : (_Float16)0.0f;
            }
            *(half8*)&As[r][c] = h;
        }
        // stage B: 256x32 halves = 1024 chunks of 8 (Wt is zero-padded to Kpad)
        #pragma unroll
        for (int tt = 0; tt < 4; tt++) {
            int f = tid + tt * 256;
            int r = f >> 2, c = (f & 3) * 8;
            *(half8*)&Bt[r][c] = *(const half8*)&Wt[(size_t)r * Kpad + k0 + c];
        }
        __syncthreads();

        half8 af[4];
        #pragma unroll
        for (int i = 0; i < 4; i++)
            af[i] = *(const half8*)&As[wm * 64 + i * 16 + lm][quad * 8];
        #pragma unroll
        for (int j = 0; j < 8; j++) {
            half8 bf = *(const half8*)&Bt[wn * 128 + j * 16 + lm][quad * 8];
            #pragma unroll
            for (int i = 0; i < 4; i++)
                acc[i][j] = __builtin_amdgcn_mfma_f32_16x16x32_f16(af[i], bf, acc[i][j], 0, 0, 0);
        }
        __syncthreads();
    }

    // epilogue: wn==0 waves hold Cn cols, wn==1 waves hold Cs cols (uniform)
    #pragma unroll
    for (int i = 0; i < 4; i++) {
        int r0 = row0 + wm * 64 + i * 16 + quad * 4;
        #pragma unroll
        for (int j = 0; j < 8; j++) {
            int c = j * 16 + lm;                       // 0..127 within the half
            float badd = wn ? bias[c] : 0.0f;
            float* dst = wn ? Cs : Cn;
            #pragma unroll
            for (int rr = 0; rr < 4; rr++) {
                int r = r0 + rr;
                if (r < M) dst[(size_t)r * HDIM + c] = acc[i][j][rr] + badd;
            }
        }
    }
}

// ------------------------------------------------------------- aggregation
__global__ void aggregate(const float* __restrict__ hn, const int* __restrict__ row_ptr,
                          const int* __restrict__ esrc, float* __restrict__ pre) {
    int n = blockIdx.x;
    int c = threadIdx.x;  // 128 channels
    int start = row_ptr[n], end = row_ptr[n + 1];
    int deg = end - start;
    __shared__ int ls[128];
    float acc = 0.0f;
    for (int base = start; base < end; base += 128) {
        int cnt = min(end - base, 128);
        __syncthreads();
        if (c < cnt) ls[c] = esrc[base + c];
        __syncthreads();
        int j = 0;
        for (; j + 4 <= cnt; j += 4) {
            float v0 = hn[ls[j] * HDIM + c];
            float v1 = hn[ls[j + 1] * HDIM + c];
            float v2 = hn[ls[j + 2] * HDIM + c];
            float v3 = hn[ls[j + 3] * HDIM + c];
            acc += (v0 + v1) + (v2 + v3);
        }
        for (; j < cnt; ++j) acc += hn[ls[j] * HDIM + c];
    }
    float denom = (float)max(deg, 1);
    pre[n * HDIM + c] += acc / denom;
}

// --------------------------------------------------------------- batch norm
__global__ void bn_stats(const float* __restrict__ P, float* __restrict__ gsum,
                         float* __restrict__ gsumsq, int M, int C) {
    int tid = threadIdx.x;
    int c = tid % C;
    int rpb = 256 / C;
    float s = 0.0f, s2 = 0.0f;
    for (int r = blockIdx.x * rpb + tid / C; r < M; r += gridDim.x * rpb) {
        float v = P[r * C + c];
        s += v;
        s2 += v * v;
    }
    __shared__ float ss[256], ss2[256];
    ss[tid] = s; ss2[tid] = s2;
    __syncthreads();
    for (int off = 128; off >= C; off >>= 1) {
        if (tid < off) { ss[tid] += ss[tid + off]; ss2[tid] += ss2[tid + off]; }
        __syncthreads();
    }
    if (tid < C) {
        atomicAdd(&gsum[tid], ss[tid]);
        atomicAdd(&gsumsq[tid], ss2[tid]);
    }
}

__global__ void bn_finalize(const float* __restrict__ gsum, const float* __restrict__ gsumsq,
                            const float* __restrict__ gamma, const float* __restrict__ beta,
                            float* __restrict__ scale, float* __restrict__ shift,
                            int M, int C) {
    int c = threadIdx.x;
    if (c < C) {
        float mean = gsum[c] / (float)M;
        float var = gsumsq[c] / (float)M - mean * mean;
        float rstd = rsqrtf(var + 1e-5f);
        float sc = rstd * gamma[c];
        scale[c] = sc;
        shift[c] = beta[c] - mean * sc;
    }
}

__global__ void bn_apply(const float* __restrict__ P, const float* __restrict__ res,
                         float* __restrict__ out, const float* __restrict__ scale,
                         const float* __restrict__ shift, int total4, int Cdiv4) {
    for (int f = blockIdx.x * blockDim.x + threadIdx.x; f < total4;
         f += gridDim.x * blockDim.x) {
        int c4 = (f % Cdiv4) * 4;
        float4 v = ((const float4*)P)[f];
        v.x = v.x * scale[c4 + 0] + shift[c4 + 0];
        v.y = v.y * scale[c4 + 1] + shift[c4 + 1];
        v.z = v.z * scale[c4 + 2] + shift[c4 + 2];
        v.w = v.w * scale[c4 + 3] + shift[c4 + 3];
        if (res) {
            float4 rv = ((const float4*)res)[f];
            v.x += rv.x; v.y += rv.y; v.z += rv.z; v.w += rv.w;
        }
        v.x = fmaxf(v.x, 0.0f); v.y = fmaxf(v.y, 0.0f);
        v.z = fmaxf(v.z, 0.0f); v.w = fmaxf(v.w, 0.0f);
        ((float4*)out)[f] = v;
    }
}

// --------------------------------------------------------------- MLP head
__global__ __launch_bounds__(256) void mlp_gemm(const float* __restrict__ H,
                                                const float* __restrict__ W1,
                                                const float* __restrict__ b1,
                                                float* __restrict__ Z, int M) {
    __shared__ float hs[64 * 132];
    __shared__ float ws[128 * 64];
    int tid = threadIdx.x;
    int tx = tid & 15;
    int ty = tid >> 4;
    int row0 = blockIdx.x * 64;

    #pragma unroll
    for (int t = 0; t < 8; t++) {
        int f = tid + t * 256;
        int r = f >> 4, c4 = (f & 15) * 4;
        *(float4*)&ws[r * 64 + c4] = *(const float4*)&W1[r * 64 + c4];
    }
    #pragma unroll
    for (int t = 0; t < 8; t++) {
        int f = tid + t * 256;
        int r = f >> 5, c4 = (f & 31) * 4;
        int gr = row0 + r;
        float4 v = {0.f, 0.f, 0.f, 0.f};
        if (gr < M) v = *(const float4*)&H[gr * HDIM + c4];
        *(float4*)&hs[r * 132 + c4] = v;
    }
    __syncthreads();

    float acc[4][4] = {};
    for (int k = 0; k < 128; k++) {
        float a[4];
        #pragma unroll
        for (int i = 0; i < 4; i++) a[i] = hs[(ty * 4 + i) * 132 + k];
        float4 b4 = *(const float4*)&ws[k * 64 + tx * 4];
        #pragma unroll
        for (int i = 0; i < 4; i++) {
            acc[i][0] += a[i] * b4.x; acc[i][1] += a[i] * b4.y;
            acc[i][2] += a[i] * b4.z; acc[i][3] += a[i] * b4.w;
        }
    }
    float4 bb = *(const float4*)&b1[tx * 4];
    #pragma unroll
    for (int i = 0; i < 4; i++) {
        int r = row0 + ty * 4 + i;
        if (r < M) {
            float4 v = {acc[i][0] + bb.x, acc[i][1] + bb.y,
                        acc[i][2] + bb.z, acc[i][3] + bb.w};
            *(float4*)&Z[r * 64 + tx * 4] = v;
        }
    }
}

__global__ void final_out(const float* __restrict__ Z, const float* __restrict__ W2,
                          const float* __restrict__ b2, float* __restrict__ out) {
    int t = blockIdx.x * blockDim.x + threadIdx.x;
    int n = t >> 6;
    int lane = t & 63;
    if (n >= N_NODES) return;
    float v = Z[n * 64 + lane] * W2[lane];
    #pragma unroll
    for (int off = 32; off >= 1; off >>= 1) v += __shfl_down(v, off, 64);
    if (lane == 0) out[n] = v + b2[0];
}

// ------------------------------------------------------------------ driver
extern "C" void kernel_launch(void* const* d_in, const int* in_sizes, int n_in,
                              void* d_out, int out_size, void* d_ws, size_t ws_size,
                              hipStream_t stream) {
    const float* X       = (const float*)d_in[0];
    const int*   graph   = (const int*)d_in[1];
    const float* Wself0  = (const float*)d_in[2];
    const float* Wneigh0 = (const float*)d_in[3];
    const float* b0      = (const float*)d_in[4];
    const float* Wself   = (const float*)d_in[5];
    const float* Wneigh  = (const float*)d_in[6];
    const float* bvec    = (const float*)d_in[7];
    const float* bn_g    = (const float*)d_in[8];
    const float* bn_b    = (const float*)d_in[9];
    const float* W1      = (const float*)d_in[10];
    const float* b1      = (const float*)d_in[11];
    const float* bng1    = (const float*)d_in[12];
    const float* bnb1    = (const float*)d_in[13];
    const float* W2      = (const float*)d_in[14];
    const float* b2      = (const float*)d_in[15];
    float* out = (float*)d_out;

    size_t off = 0;
    auto alloc = [&](size_t bytes) {
        void* p = (char*)d_ws + off;
        off += (bytes + 255) & ~(size_t)255;
        return p;
    };
    int* cnt     = (int*)alloc(N_NODES * 4);
    int* cursor  = (int*)alloc(N_NODES * 4);
    int* row_ptr = (int*)alloc((N_NODES + 1) * 4);
    int* incl    = (int*)alloc(N_NODES * 4);
    int* blk     = (int*)alloc(NB_SCAN * 4);
    int* blkoff  = (int*)alloc(NB_SCAN * 4);
    int* esrc    = (int*)alloc((size_t)N_EDGES * 4);
    float* B0    = (float*)alloc((size_t)N_NODES * HDIM * 4);
    float* B1    = (float*)alloc((size_t)N_NODES * HDIM * 4);
    float* B2    = (float*)alloc((size_t)N_NODES * HDIM * 4);
    float* Z     = (float*)alloc((size_t)N_NODES * 64 * 4);
    _Float16* Wt0 = (_Float16*)alloc((size_t)256 * KPAD0 * 2);
    _Float16* Wtl = (_Float16*)alloc((size_t)3 * 256 * 128 * 2);
    float* stats = (float*)alloc(512 * 4);
    float* gsum = stats, *gsumsq = stats + 128, *scale = stats + 256, *shift = stats + 384;

    const int EB = (N_EDGES + 255) / 256;
    const int GB = (N_NODES + GBM - 1) / GBM;   // 782

    // CSR build
    hipMemsetAsync(cnt, 0, N_NODES * 4, stream);
    hipMemsetAsync(cursor, 0, N_NODES * 4, stream);
    count_edges<<<EB, 256, 0, stream>>>(graph, cnt);
    scan1<<<NB_SCAN, SCAN_B, 0, stream>>>(cnt, incl, blk);
    scan2<<<1, 512, 0, stream>>>(blk, blkoff);
    scan3<<<NB_SCAN, SCAN_B, 0, stream>>>(incl, blkoff, row_ptr);
    fill_edges<<<EB, 256, 0, stream>>>(graph, row_ptr, cursor, esrc);

    // weight packs (fp16, transposed, padded)
    build_wt0<<<(256 * KPAD0 + 255) / 256, 256, 0, stream>>>(Wneigh0, Wself0, Wt0);
    build_wtl<<<(3 * 256 * 128 + 255) / 256, 256, 0, stream>>>(Wneigh, Wself, Wtl);

    float* h   = B0;
    float* hn  = B1;
    float* pre = B2;

    // ---- layer 0 (K = 700)
    dual_gemm_mfma<<<GB, 256, 0, stream>>>(X, N_NODES, F_IN, KPAD0, Wt0, b0, hn, pre);
    aggregate<<<N_NODES, 128, 0, stream>>>(hn, row_ptr, esrc, pre);
    hipMemsetAsync(stats, 0, 256 * 4, stream);
    bn_stats<<<512, 256, 0, stream>>>(pre, gsum, gsumsq, N_NODES, 128);
    bn_finalize<<<1, 128, 0, stream>>>(gsum, gsumsq, bn_g, bn_b, scale, shift, N_NODES, 128);
    bn_apply<<<1024, 256, 0, stream>>>(pre, nullptr, h, scale, shift,
                                       N_NODES * HDIM / 4, HDIM / 4);

    // ---- layers 1..3 (K = 128, residual)
    for (int l = 0; l < 3; l++) {
        dual_gemm_mfma<<<GB, 256, 0, stream>>>(h, N_NODES, HDIM, HDIM,
                                               Wtl + (size_t)l * 256 * 128,
                                               bvec + l * HDIM, hn, pre);
        aggregate<<<N_NODES, 128, 0, stream>>>(hn, row_ptr, esrc, pre);
        hipMemsetAsync(stats, 0, 256 * 4, stream);
        bn_stats<<<512, 256, 0, stream>>>(pre, gsum, gsumsq, N_NODES, 128);
        bn_finalize<<<1, 128, 0, stream>>>(gsum, gsumsq, bn_g + (l + 1) * HDIM,
                                           bn_b + (l + 1) * HDIM, scale, shift,
                                           N_NODES, 128);
        bn_apply<<<1024, 256, 0, stream>>>(pre, h, pre, scale, shift,
                                           N_NODES * HDIM / 4, HDIM / 4);
        float* t = h; h = pre; pre = t;
    }

    // ---- MLP head
    mlp_gemm<<<(N_NODES + 63) / 64, 256, 0, stream>>>(h, W1, b1, Z, N_NODES);
    hipMemsetAsync(stats, 0, 256 * 4, stream);
    bn_stats<<<512, 256, 0, stream>>>(Z, gsum, gsumsq, N_NODES, 64);
    bn_finalize<<<1, 64, 0, stream>>>(gsum, gsumsq, bng1, bnb1, scale, shift, N_NODES, 64);
    bn_apply<<<1024, 256, 0, stream>>>(Z, nullptr, Z, scale, shift,
                                       N_NODES * 64 / 4, 64 / 4);
    final_out<<<(N_NODES * 64) / 256, 256, 0, stream>>>(Z, W2, b2, out);
}

// Round 3
// 1698.360 us; speedup vs baseline: 1.2964x; 1.1054x over previous
//
#include <hip/hip_runtime.h>
#include <hip/hip_bf16.h>

#define N_NODES 100000
#define N_EDGES 1600000
#define F_IN    700
#define KPAD0   704
#define NKB0    22          // 704/32
#define HDIM    128
#define SCAN_B  256
#define NB_SCAN ((N_NODES + SCAN_B - 1) / SCAN_B)   // 391

typedef _Float16 half8 __attribute__((ext_vector_type(8)));
typedef _Float16 half4 __attribute__((ext_vector_type(4)));
typedef float floatx4 __attribute__((ext_vector_type(4)));

// async global->LDS, 16B per lane; dst slot = wave-uniform base + lane*16
__device__ __forceinline__ void cp16(const void* g, void* l) {
    __builtin_amdgcn_global_load_lds(
        (const __attribute__((address_space(1))) void*)g,
        (__attribute__((address_space(3))) void*)l, 16, 0, 0);
}

// ---------------------------------------------------------------- CSR build
__global__ void count_edges(const int* __restrict__ graph, int* __restrict__ cnt) {
    int e = blockIdx.x * blockDim.x + threadIdx.x;
    if (e < N_EDGES) atomicAdd(&cnt[graph[2 * e + 1]], 1);
}

__global__ void scan1(const int* __restrict__ cnt, int* __restrict__ incl,
                      int* __restrict__ blk) {
    __shared__ int s[SCAN_B];
    int tid = threadIdx.x;
    int i = blockIdx.x * SCAN_B + tid;
    s[tid] = (i < N_NODES) ? cnt[i] : 0;
    __syncthreads();
    for (int off = 1; off < SCAN_B; off <<= 1) {
        int t = (tid >= off) ? s[tid - off] : 0;
        __syncthreads();
        s[tid] += t;
        __syncthreads();
    }
    if (i < N_NODES) incl[i] = s[tid];
    if (tid == SCAN_B - 1) blk[blockIdx.x] = s[tid];
}

__global__ void scan2(const int* __restrict__ blk, int* __restrict__ blkoff) {
    __shared__ int s[512];
    int tid = threadIdx.x;
    s[tid] = (tid < NB_SCAN) ? blk[tid] : 0;
    __syncthreads();
    for (int off = 1; off < 512; off <<= 1) {
        int t = (tid >= off) ? s[tid - off] : 0;
        __syncthreads();
        s[tid] += t;
        __syncthreads();
    }
    if (tid < NB_SCAN) blkoff[tid] = (tid == 0) ? 0 : s[tid - 1];
}

__global__ void scan3(const int* __restrict__ incl, const int* __restrict__ blkoff,
                      int* __restrict__ row_ptr) {
    int i = blockIdx.x * SCAN_B + threadIdx.x;
    if (i < N_NODES) {
        row_ptr[i + 1] = incl[i] + blkoff[i >> 8];
        if (i == 0) row_ptr[0] = 0;
    }
}

__global__ void fill_edges(const int* __restrict__ graph, const int* __restrict__ row_ptr,
                           int* __restrict__ cursor, int* __restrict__ esrc) {
    int e = blockIdx.x * blockDim.x + threadIdx.x;
    if (e < N_EDGES) {
        int src = graph[2 * e];
        int dst = graph[2 * e + 1];
        esrc[row_ptr[dst] + atomicAdd(&cursor[dst], 1)] = src;
    }
}

// ------------------------------------------------- X -> fp16 (padded to 704)
__global__ void convert_x(const float* __restrict__ X, _Float16* __restrict__ Xh) {
    const long total = (long)N_NODES * (KPAD0 / 4);
    for (long idx = (long)blockIdx.x * blockDim.x + threadIdx.x; idx < total;
         idx += (long)gridDim.x * blockDim.x) {
        long n = idx / (KPAD0 / 4);
        int c4 = (int)(idx % (KPAD0 / 4));
        half4 h;
        if (c4 * 4 + 3 < F_IN) {
            float4 v = *(const float4*)&X[n * F_IN + c4 * 4];
            h[0] = (_Float16)v.x; h[1] = (_Float16)v.y;
            h[2] = (_Float16)v.z; h[3] = (_Float16)v.w;
        } else {
            h[0] = h[1] = h[2] = h[3] = (_Float16)0.0f;
        }
        *(half4*)&Xh[n * KPAD0 + c4 * 4] = h;
    }
}

// ------------------- weight packs: tile-major, XOR-swizzled LDS image (fp16)
// chunk layout: out[((kb*256 + r)*4 + cc)*8 + e] = W[k = kb*32 + (cc^((r>>1)&3))*8 + e][col r]
__global__ void build_wtp0(const float* __restrict__ Wn, const float* __restrict__ Ws,
                           _Float16* __restrict__ out) {
    int q = blockIdx.x * blockDim.x + threadIdx.x;
    if (q >= NKB0 * 256 * 4) return;
    int kb = q >> 10;
    int r  = (q >> 2) & 255;
    int cc = q & 3;
    int k0 = kb * 32 + (cc ^ ((r >> 1) & 3)) * 8;
    half8 v;
    #pragma unroll
    for (int e = 0; e < 8; e++) {
        int k = k0 + e;
        float f = 0.0f;
        if (k < F_IN) f = (r < 128) ? Wn[k * 128 + r] : Ws[k * 128 + (r - 128)];
        v[e] = (_Float16)f;
    }
    *(half8*)&out[(size_t)q * 8] = v;
}

__global__ void build_wtpl(const float* __restrict__ Wn, const float* __restrict__ Ws,
                           _Float16* __restrict__ out) {
    int q = blockIdx.x * blockDim.x + threadIdx.x;
    if (q >= 3 * 4 * 256 * 4) return;
    int l = q >> 12;
    int rem = q & 4095;
    int kb = rem >> 10;
    int r  = (rem >> 2) & 255;
    int cc = rem & 3;
    int k0 = kb * 32 + (cc ^ ((r >> 1) & 3)) * 8;
    half8 v;
    #pragma unroll
    for (int e = 0; e < 8; e++) {
        int k = k0 + e;
        float f = (r < 128) ? Wn[l * 16384 + k * 128 + r]
                            : Ws[l * 16384 + k * 128 + (r - 128)];
        v[e] = (_Float16)f;
    }
    *(half8*)&out[(size_t)q * 8] = v;
}

// -------------------------------------- fused dual MFMA GEMM, async + dbuf
// Cn(fp16) = A @ Wt[0:128]^T ; Cs(fp32) = A @ Wt[128:256]^T + bias
// A: M x Kpad fp16 row-major. Wtp: pre-tiled/swizzled LDS image, 16KB per kb.
#define GBM 128
__global__ __launch_bounds__(256) void dual_gemm_mfma(
    const _Float16* __restrict__ A, int M, int Kpad, int NKB,
    const _Float16* __restrict__ Wtp, const float* __restrict__ bias,
    _Float16* __restrict__ Cn, float* __restrict__ Cs) {
    // per buffer: A tile 128x32 halves (8KB) at [0], B tile 256x32 (16KB) at [4096]
    __shared__ _Float16 sbuf[2][12288];

    int tid = threadIdx.x;
    int wave = tid >> 6, lane = tid & 63;
    int lm = lane & 15, quad = lane >> 4;
    int wm = wave >> 1, wn = wave & 1;      // 2x2 waves: 64 rows x 128 cols each
    long row0 = (long)blockIdx.x * GBM;

    floatx4 acc[4][8] = {};

    auto stage = [&](int kb, _Float16* buf) {
        // A: 512 chunks of 16B, swizzled source columns
        #pragma unroll
        for (int pass = 0; pass < 2; pass++) {
            int q = pass * 256 + tid;
            int r = q >> 2, cc = q & 3;
            int ccg = cc ^ ((r >> 1) & 3);
            long grow = row0 + r;
            _Float16* dst = buf + pass * 2048 + wave * 512;
            if (grow < M)
                cp16(A + grow * (long)Kpad + kb * 32 + ccg * 8, dst);
        }
        // B: 1024 chunks, fully linear (pre-swizzled at pack time)
        const _Float16* wsrc = Wtp + (size_t)kb * 8192;
        #pragma unroll
        for (int pass = 0; pass < 4; pass++) {
            cp16(wsrc + (size_t)(pass * 256 + tid) * 8,
                 buf + 4096 + pass * 2048 + wave * 512);
        }
    };

    stage(0, sbuf[0]);
    __syncthreads();

    for (int kb = 0; kb < NKB; kb++) {
        int p = kb & 1;
        if (kb + 1 < NKB) stage(kb + 1, sbuf[p ^ 1]);

        const _Float16* bp = sbuf[p];
        half8 af[4];
        #pragma unroll
        for (int i = 0; i < 4; i++) {
            int row = wm * 64 + i * 16 + lm;
            int ch = quad ^ ((row >> 1) & 3);
            af[i] = *(const half8*)&bp[row * 32 + ch * 8];
        }
        #pragma unroll
        for (int j = 0; j < 8; j++) {
            int brow = wn * 128 + j * 16 + lm;
            int ch = quad ^ ((brow >> 1) & 3);
            half8 bf = *(const half8*)&bp[4096 + brow * 32 + ch * 8];
            #pragma unroll
            for (int i = 0; i < 4; i++)
                acc[i][j] = __builtin_amdgcn_mfma_f32_16x16x32_f16(af[i], bf, acc[i][j], 0, 0, 0);
        }
        __syncthreads();
    }

    #pragma unroll
    for (int i = 0; i < 4; i++) {
        long r0 = row0 + wm * 64 + i * 16 + quad * 4;
        #pragma unroll
        for (int j = 0; j < 8; j++) {
            int c = j * 16 + lm;
            if (wn) {
                float badd = bias[c];
                #pragma unroll
                for (int rr = 0; rr < 4; rr++) {
                    long r = r0 + rr;
                    if (r < M) Cs[r * HDIM + c] = acc[i][j][rr] + badd;
                }
            } else {
                #pragma unroll
                for (int rr = 0; rr < 4; rr++) {
                    long r = r0 + rr;
                    if (r < M) Cn[r * HDIM + c] = (_Float16)acc[i][j][rr];
                }
            }
        }
    }
}

// ------------------------------------------------------------- aggregation
// pre[n,:] += (sum over incoming edges of hn16[src,:]) / max(deg,1)
__global__ void aggregate(const _Float16* __restrict__ hn, const int* __restrict__ row_ptr,
                          const int* __restrict__ esrc, float* __restrict__ pre) {
    int n = blockIdx.x;
    int c = threadIdx.x;  // 128 channels
    int start = row_ptr[n], end = row_ptr[n + 1];
    int deg = end - start;
    __shared__ int ls[128];
    float acc = 0.0f;
    for (int base = start; base < end; base += 128) {
        int cnt = min(end - base, 128);
        __syncthreads();
        if (c < cnt) ls[c] = esrc[base + c];
        __syncthreads();
        int j = 0;
        for (; j + 4 <= cnt; j += 4) {
            float v0 = (float)hn[(size_t)ls[j] * HDIM + c];
            float v1 = (float)hn[(size_t)ls[j + 1] * HDIM + c];
            float v2 = (float)hn[(size_t)ls[j + 2] * HDIM + c];
            float v3 = (float)hn[(size_t)ls[j + 3] * HDIM + c];
            acc += (v0 + v1) + (v2 + v3);
        }
        for (; j < cnt; ++j) acc += (float)hn[(size_t)ls[j] * HDIM + c];
    }
    float denom = (float)max(deg, 1);
    pre[(size_t)n * HDIM + c] += acc / denom;
}

// --------------------------------------------------------------- batch norm
__global__ void bn_stats(const float* __restrict__ P, float* __restrict__ gsum,
                         float* __restrict__ gsumsq, int M, int C) {
    int tid = threadIdx.x;
    int c = tid % C;
    int rpb = 256 / C;
    float s = 0.0f, s2 = 0.0f;
    for (int r = blockIdx.x * rpb + tid / C; r < M; r += gridDim.x * rpb) {
        float v = P[(size_t)r * C + c];
        s += v; s2 += v * v;
    }
    __shared__ float ss[256], ss2[256];
    ss[tid] = s; ss2[tid] = s2;
    __syncthreads();
    for (int off = 128; off >= C; off >>= 1) {
        if (tid < off) { ss[tid] += ss[tid + off]; ss2[tid] += ss2[tid + off]; }
        __syncthreads();
    }
    if (tid < C) {
        atomicAdd(&gsum[tid], ss[tid]);
        atomicAdd(&gsumsq[tid], ss2[tid]);
    }
}

__global__ void bn_finalize(const float* __restrict__ gsum, const float* __restrict__ gsumsq,
                            const float* __restrict__ gamma, const float* __restrict__ beta,
                            float* __restrict__ scale, float* __restrict__ shift,
                            int M, int C) {
    int c = threadIdx.x;
    if (c < C) {
        float mean = gsum[c] / (float)M;
        float var = gsumsq[c] / (float)M - mean * mean;
        float sc = rsqrtf(var + 1e-5f) * gamma[c];
        scale[c] = sc;
        shift[c] = beta[c] - mean * sc;
    }
}

// out = relu(P*scale+shift [+ res]); optional fp16 copy for next GEMM
__global__ void bn_apply(const float* __restrict__ P, const float* __restrict__ res,
                         float* __restrict__ out, _Float16* __restrict__ out16,
                         const float* __restrict__ scale, const float* __restrict__ shift,
                         int total4, int Cdiv4) {
    for (int f = blockIdx.x * blockDim.x + threadIdx.x; f < total4;
         f += gridDim.x * blockDim.x) {
        int c4 = (f % Cdiv4) * 4;
        float4 v = ((const float4*)P)[f];
        v.x = v.x * scale[c4 + 0] + shift[c4 + 0];
        v.y = v.y * scale[c4 + 1] + shift[c4 + 1];
        v.z = v.z * scale[c4 + 2] + shift[c4 + 2];
        v.w = v.w * scale[c4 + 3] + shift[c4 + 3];
        if (res) {
            float4 rv = ((const float4*)res)[f];
            v.x += rv.x; v.y += rv.y; v.z += rv.z; v.w += rv.w;
        }
        v.x = fmaxf(v.x, 0.0f); v.y = fmaxf(v.y, 0.0f);
        v.z = fmaxf(v.z, 0.0f); v.w = fmaxf(v.w, 0.0f);
        ((float4*)out)[f] = v;
        if (out16) {
            half4 h;
            h[0] = (_Float16)v.x; h[1] = (_Float16)v.y;
            h[2] = (_Float16)v.z; h[3] = (_Float16)v.w;
            *(half4*)&out16[(size_t)f * 4] = h;
        }
    }
}

// --------------------------------------------------------------- MLP head
__global__ __launch_bounds__(256) void mlp_gemm(const float* __restrict__ H,
                                                const float* __restrict__ W1,
                                                const float* __restrict__ b1,
                                                float* __restrict__ Z, int M) {
    __shared__ float hs[64 * 132];
    __shared__ float ws[128 * 64];
    int tid = threadIdx.x;
    int tx = tid & 15;
    int ty = tid >> 4;
    int row0 = blockIdx.x * 64;

    #pragma unroll
    for (int t = 0; t < 8; t++) {
        int f = tid + t * 256;
        int r = f >> 4, c4 = (f & 15) * 4;
        *(float4*)&ws[r * 64 + c4] = *(const float4*)&W1[r * 64 + c4];
    }
    #pragma unroll
    for (int t = 0; t < 8; t++) {
        int f = tid + t * 256;
        int r = f >> 5, c4 = (f & 31) * 4;
        int gr = row0 + r;
        float4 v = {0.f, 0.f, 0.f, 0.f};
        if (gr < M) v = *(const float4*)&H[(size_t)gr * HDIM + c4];
        *(float4*)&hs[r * 132 + c4] = v;
    }
    __syncthreads();

    float acc[4][4] = {};
    for (int k = 0; k < 128; k++) {
        float a[4];
        #pragma unroll
        for (int i = 0; i < 4; i++) a[i] = hs[(ty * 4 + i) * 132 + k];
        float4 b4 = *(const float4*)&ws[k * 64 + tx * 4];
        #pragma unroll
        for (int i = 0; i < 4; i++) {
            acc[i][0] += a[i] * b4.x; acc[i][1] += a[i] * b4.y;
            acc[i][2] += a[i] * b4.z; acc[i][3] += a[i] * b4.w;
        }
    }
    float4 bb = *(const float4*)&b1[tx * 4];
    #pragma unroll
    for (int i = 0; i < 4; i++) {
        int r = row0 + ty * 4 + i;
        if (r < M) {
            float4 v = {acc[i][0] + bb.x, acc[i][1] + bb.y,
                        acc[i][2] + bb.z, acc[i][3] + bb.w};
            *(float4*)&Z[(size_t)r * 64 + tx * 4] = v;
        }
    }
}

__global__ void final_out(const float* __restrict__ Z, const float* __restrict__ W2,
                          const float* __restrict__ b2, float* __restrict__ out) {
    int t = blockIdx.x * blockDim.x + threadIdx.x;
    int n = t >> 6;
    int lane = t & 63;
    if (n >= N_NODES) return;
    float v = Z[(size_t)n * 64 + lane] * W2[lane];
    #pragma unroll
    for (int off = 32; off >= 1; off >>= 1) v += __shfl_down(v, off, 64);
    if (lane == 0) out[n] = v + b2[0];
}

// ------------------------------------------------------------------ driver
extern "C" void kernel_launch(void* const* d_in, const int* in_sizes, int n_in,
                              void* d_out, int out_size, void* d_ws, size_t ws_size,
                              hipStream_t stream) {
    const float* X       = (const float*)d_in[0];
    const int*   graph   = (const int*)d_in[1];
    const float* Wself0  = (const float*)d_in[2];
    const float* Wneigh0 = (const float*)d_in[3];
    const float* b0      = (const float*)d_in[4];
    const float* Wself   = (const float*)d_in[5];
    const float* Wneigh  = (const float*)d_in[6];
    const float* bvec    = (const float*)d_in[7];
    const float* bn_g    = (const float*)d_in[8];
    const float* bn_b    = (const float*)d_in[9];
    const float* W1      = (const float*)d_in[10];
    const float* b1      = (const float*)d_in[11];
    const float* bng1    = (const float*)d_in[12];
    const float* bnb1    = (const float*)d_in[13];
    const float* W2      = (const float*)d_in[14];
    const float* b2      = (const float*)d_in[15];
    float* out = (float*)d_out;

    size_t off = 0;
    auto alloc = [&](size_t bytes) {
        void* p = (char*)d_ws + off;
        off += (bytes + 255) & ~(size_t)255;
        return p;
    };
    int* cnt     = (int*)alloc(N_NODES * 4);
    int* cursor  = (int*)alloc(N_NODES * 4);
    int* row_ptr = (int*)alloc((N_NODES + 1) * 4);
    int* incl    = (int*)alloc(N_NODES * 4);
    int* blk     = (int*)alloc(NB_SCAN * 4);
    int* blkoff  = (int*)alloc(NB_SCAN * 4);
    int* esrc    = (int*)alloc((size_t)N_EDGES * 4);
    // Xh region (dead after layer-0 GEMM) is reused for h / h16 / Z
    char* xh_region = (char*)alloc((size_t)N_NODES * KPAD0 * 2);   // 140.8 MB
    _Float16* Xh  = (_Float16*)xh_region;
    float*    hA  = (float*)xh_region;                              // 51.2 MB
    _Float16* h16 = (_Float16*)(xh_region + (size_t)N_NODES * HDIM * 4);      // 25.6 MB
    float*    Z   = (float*)(xh_region + (size_t)N_NODES * HDIM * 6);         // 25.6 MB
    float*    hB  = (float*)alloc((size_t)N_NODES * HDIM * 4);     // pre buffer
    _Float16* hn16 = (_Float16*)alloc((size_t)N_NODES * HDIM * 2);
    _Float16* Wtp0 = (_Float16*)alloc((size_t)NKB0 * 8192 * 2);
    _Float16* Wtpl = (_Float16*)alloc((size_t)3 * 4 * 8192 * 2);
    float* stats = (float*)alloc(512 * 4);
    float* gsum = stats, *gsumsq = stats + 128, *scale = stats + 256, *shift = stats + 384;

    const int EB = (N_EDGES + 255) / 256;
    const int GB = (N_NODES + GBM - 1) / GBM;   // 782

    // CSR build
    hipMemsetAsync(cnt, 0, N_NODES * 4, stream);
    hipMemsetAsync(cursor, 0, N_NODES * 4, stream);
    count_edges<<<EB, 256, 0, stream>>>(graph, cnt);
    scan1<<<NB_SCAN, SCAN_B, 0, stream>>>(cnt, incl, blk);
    scan2<<<1, 512, 0, stream>>>(blk, blkoff);
    scan3<<<NB_SCAN, SCAN_B, 0, stream>>>(incl, blkoff, row_ptr);
    fill_edges<<<EB, 256, 0, stream>>>(graph, row_ptr, cursor, esrc);

    // weight packs + X conversion
    build_wtp0<<<(NKB0 * 1024 + 255) / 256, 256, 0, stream>>>(Wneigh0, Wself0, Wtp0);
    build_wtpl<<<(3 * 4096 + 255) / 256, 256, 0, stream>>>(Wneigh, Wself, Wtpl);
    convert_x<<<2048, 256, 0, stream>>>(X, Xh);

    float* h   = hA;
    float* pre = hB;

    // ---- layer 0 (Kpad = 704)
    dual_gemm_mfma<<<GB, 256, 0, stream>>>(Xh, N_NODES, KPAD0, NKB0, Wtp0, b0, hn16, pre);
    aggregate<<<N_NODES, 128, 0, stream>>>(hn16, row_ptr, esrc, pre);
    hipMemsetAsync(stats, 0, 256 * 4, stream);
    bn_stats<<<512, 256, 0, stream>>>(pre, gsum, gsumsq, N_NODES, 128);
    bn_finalize<<<1, 128, 0, stream>>>(gsum, gsumsq, bn_g, bn_b, scale, shift, N_NODES, 128);
    bn_apply<<<1024, 256, 0, stream>>>(pre, nullptr, h, h16, scale, shift,
                                       N_NODES * HDIM / 4, HDIM / 4);

    // ---- layers 1..3 (Kpad = 128, residual)
    for (int l = 0; l < 3; l++) {
        dual_gemm_mfma<<<GB, 256, 0, stream>>>(h16, N_NODES, HDIM, 4,
                                               Wtpl + (size_t)l * 32768,
                                               bvec + l * HDIM, hn16, pre);
        aggregate<<<N_NODES, 128, 0, stream>>>(hn16, row_ptr, esrc, pre);
        hipMemsetAsync(stats, 0, 256 * 4, stream);
        bn_stats<<<512, 256, 0, stream>>>(pre, gsum, gsumsq, N_NODES, 128);
        bn_finalize<<<1, 128, 0, stream>>>(gsum, gsumsq, bn_g + (l + 1) * HDIM,
                                           bn_b + (l + 1) * HDIM, scale, shift,
                                           N_NODES, 128);
        bn_apply<<<1024, 256, 0, stream>>>(pre, h, pre, h16, scale, shift,
                                           N_NODES * HDIM / 4, HDIM / 4);
        float* t = h; h = pre; pre = t;
    }

    // ---- MLP head
    mlp_gemm<<<(N_NODES + 63) / 64, 256, 0, stream>>>(h, W1, b1, Z, N_NODES);
    hipMemsetAsync(stats, 0, 256 * 4, stream);
    bn_stats<<<512, 256, 0, stream>>>(Z, gsum, gsumsq, N_NODES, 64);
    bn_finalize<<<1, 64, 0, stream>>>(gsum, gsumsq, bng1, bnb1, scale, shift, N_NODES, 64);
    bn_apply<<<1024, 256, 0, stream>>>(Z, nullptr, Z, nullptr, scale, shift,
                                       N_NODES * 64 / 4, 64 / 4);
    final_out<<<(N_NODES * 64) / 256, 256, 0, stream>>>(Z, W2, b2, out);
}

// Round 4
// 1600.623 us; speedup vs baseline: 1.3756x; 1.0611x over previous
//
#include <hip/hip_runtime.h>
#include <hip/hip_bf16.h>

#define N_NODES 100000
#define N_EDGES 1600000
#define F_IN    700
#define KPAD0   704
#define NKB0    22          // 704/32
#define HDIM    128
#define SCAN_B  256
#define NB_SCAN ((N_NODES + SCAN_B - 1) / SCAN_B)   // 391

typedef _Float16 half8 __attribute__((ext_vector_type(8)));
typedef _Float16 half4 __attribute__((ext_vector_type(4)));
typedef float floatx4 __attribute__((ext_vector_type(4)));

// async global->LDS, 16B per lane; dst slot = wave-uniform base + lane*16
__device__ __forceinline__ void cp16(const void* g, void* l) {
    __builtin_amdgcn_global_load_lds(
        (const __attribute__((address_space(1))) void*)g,
        (__attribute__((address_space(3))) void*)l, 16, 0, 0);
}

// ---------------------------------------------------------------- CSR build
__global__ void count_edges(const int* __restrict__ graph, int* __restrict__ cnt) {
    int e = blockIdx.x * blockDim.x + threadIdx.x;
    if (e < N_EDGES) atomicAdd(&cnt[graph[2 * e + 1]], 1);
}

__global__ void scan1(const int* __restrict__ cnt, int* __restrict__ incl,
                      int* __restrict__ blk) {
    __shared__ int s[SCAN_B];
    int tid = threadIdx.x;
    int i = blockIdx.x * SCAN_B + tid;
    s[tid] = (i < N_NODES) ? cnt[i] : 0;
    __syncthreads();
    for (int off = 1; off < SCAN_B; off <<= 1) {
        int t = (tid >= off) ? s[tid - off] : 0;
        __syncthreads();
        s[tid] += t;
        __syncthreads();
    }
    if (i < N_NODES) incl[i] = s[tid];
    if (tid == SCAN_B - 1) blk[blockIdx.x] = s[tid];
}

__global__ void scan2(const int* __restrict__ blk, int* __restrict__ blkoff) {
    __shared__ int s[512];
    int tid = threadIdx.x;
    s[tid] = (tid < NB_SCAN) ? blk[tid] : 0;
    __syncthreads();
    for (int off = 1; off < 512; off <<= 1) {
        int t = (tid >= off) ? s[tid - off] : 0;
        __syncthreads();
        s[tid] += t;
        __syncthreads();
    }
    if (tid < NB_SCAN) blkoff[tid] = (tid == 0) ? 0 : s[tid - 1];
}

__global__ void scan3(const int* __restrict__ incl, const int* __restrict__ blkoff,
                      int* __restrict__ row_ptr) {
    int i = blockIdx.x * SCAN_B + threadIdx.x;
    if (i < N_NODES) {
        row_ptr[i + 1] = incl[i] + blkoff[i >> 8];
        if (i == 0) row_ptr[0] = 0;
    }
}

__global__ void fill_edges(const int* __restrict__ graph, const int* __restrict__ row_ptr,
                           int* __restrict__ cursor, int* __restrict__ esrc) {
    int e = blockIdx.x * blockDim.x + threadIdx.x;
    if (e < N_EDGES) {
        int src = graph[2 * e];
        int dst = graph[2 * e + 1];
        esrc[row_ptr[dst] + atomicAdd(&cursor[dst], 1)] = src;
    }
}

// ------------------------------------------------- X -> fp16 (padded to 704)
__global__ void convert_x(const float* __restrict__ X, _Float16* __restrict__ Xh) {
    const long total = (long)N_NODES * (KPAD0 / 4);
    for (long idx = (long)blockIdx.x * blockDim.x + threadIdx.x; idx < total;
         idx += (long)gridDim.x * blockDim.x) {
        long n = idx / (KPAD0 / 4);
        int c4 = (int)(idx % (KPAD0 / 4));
        half4 h;
        if (c4 * 4 + 3 < F_IN) {
            float4 v = *(const float4*)&X[n * F_IN + c4 * 4];
            h[0] = (_Float16)v.x; h[1] = (_Float16)v.y;
            h[2] = (_Float16)v.z; h[3] = (_Float16)v.w;
        } else {
            h[0] = h[1] = h[2] = h[3] = (_Float16)0.0f;
        }
        *(half4*)&Xh[n * KPAD0 + c4 * 4] = h;
    }
}

// ------------------- weight packs: tile-major, XOR-swizzled LDS image (fp16)
__global__ void build_wtp0(const float* __restrict__ Wn, const float* __restrict__ Ws,
                           _Float16* __restrict__ out) {
    int q = blockIdx.x * blockDim.x + threadIdx.x;
    if (q >= NKB0 * 256 * 4) return;
    int kb = q >> 10;
    int r  = (q >> 2) & 255;
    int cc = q & 3;
    int k0 = kb * 32 + (cc ^ ((r >> 1) & 3)) * 8;
    half8 v;
    #pragma unroll
    for (int e = 0; e < 8; e++) {
        int k = k0 + e;
        float f = 0.0f;
        if (k < F_IN) f = (r < 128) ? Wn[k * 128 + r] : Ws[k * 128 + (r - 128)];
        v[e] = (_Float16)f;
    }
    *(half8*)&out[(size_t)q * 8] = v;
}

__global__ void build_wtpl(const float* __restrict__ Wn, const float* __restrict__ Ws,
                           _Float16* __restrict__ out) {
    int q = blockIdx.x * blockDim.x + threadIdx.x;
    if (q >= 3 * 4 * 256 * 4) return;
    int l = q >> 12;
    int rem = q & 4095;
    int kb = rem >> 10;
    int r  = (rem >> 2) & 255;
    int cc = rem & 3;
    int k0 = kb * 32 + (cc ^ ((r >> 1) & 3)) * 8;
    half8 v;
    #pragma unroll
    for (int e = 0; e < 8; e++) {
        int k = k0 + e;
        float f = (r < 128) ? Wn[l * 16384 + k * 128 + r]
                            : Ws[l * 16384 + k * 128 + (r - 128)];
        v[e] = (_Float16)f;
    }
    *(half8*)&out[(size_t)q * 8] = v;
}

// -------------------------------------- fused dual MFMA GEMM, async + dbuf
#define GBM 128
__global__ __launch_bounds__(256) void dual_gemm_mfma(
    const _Float16* __restrict__ A, int M, int Kpad, int NKB,
    const _Float16* __restrict__ Wtp, const float* __restrict__ bias,
    _Float16* __restrict__ Cn, float* __restrict__ Cs) {
    __shared__ _Float16 sbuf[2][12288];

    int tid = threadIdx.x;
    int wave = tid >> 6, lane = tid & 63;
    int lm = lane & 15, quad = lane >> 4;
    int wm = wave >> 1, wn = wave & 1;
    long row0 = (long)blockIdx.x * GBM;

    floatx4 acc[4][8] = {};

    auto stage = [&](int kb, _Float16* buf) {
        #pragma unroll
        for (int pass = 0; pass < 2; pass++) {
            int q = pass * 256 + tid;
            int r = q >> 2, cc = q & 3;
            int ccg = cc ^ ((r >> 1) & 3);
            long grow = row0 + r;
            _Float16* dst = buf + pass * 2048 + wave * 512;
            if (grow < M)
                cp16(A + grow * (long)Kpad + kb * 32 + ccg * 8, dst);
        }
        const _Float16* wsrc = Wtp + (size_t)kb * 8192;
        #pragma unroll
        for (int pass = 0; pass < 4; pass++) {
            cp16(wsrc + (size_t)(pass * 256 + tid) * 8,
                 buf + 4096 + pass * 2048 + wave * 512);
        }
    };

    stage(0, sbuf[0]);
    __syncthreads();

    for (int kb = 0; kb < NKB; kb++) {
        int p = kb & 1;
        if (kb + 1 < NKB) stage(kb + 1, sbuf[p ^ 1]);

        const _Float16* bp = sbuf[p];
        half8 af[4];
        #pragma unroll
        for (int i = 0; i < 4; i++) {
            int row = wm * 64 + i * 16 + lm;
            int ch = quad ^ ((row >> 1) & 3);
            af[i] = *(const half8*)&bp[row * 32 + ch * 8];
        }
        #pragma unroll
        for (int j = 0; j < 8; j++) {
            int brow = wn * 128 + j * 16 + lm;
            int ch = quad ^ ((brow >> 1) & 3);
            half8 bf = *(const half8*)&bp[4096 + brow * 32 + ch * 8];
            #pragma unroll
            for (int i = 0; i < 4; i++)
                acc[i][j] = __builtin_amdgcn_mfma_f32_16x16x32_f16(af[i], bf, acc[i][j], 0, 0, 0);
        }
        __syncthreads();
    }

    #pragma unroll
    for (int i = 0; i < 4; i++) {
        long r0 = row0 + wm * 64 + i * 16 + quad * 4;
        #pragma unroll
        for (int j = 0; j < 8; j++) {
            int c = j * 16 + lm;
            if (wn) {
                float badd = bias[c];
                #pragma unroll
                for (int rr = 0; rr < 4; rr++) {
                    long r = r0 + rr;
                    if (r < M) Cs[r * HDIM + c] = acc[i][j][rr] + badd;
                }
            } else {
                #pragma unroll
                for (int rr = 0; rr < 4; rr++) {
                    long r = r0 + rr;
                    if (r < M) Cn[r * HDIM + c] = (_Float16)acc[i][j][rr];
                }
            }
        }
    }
}

// ------------------------------------------------------------- aggregation
// wave-per-node; lane = (edge slot: lane>>4, channel group: (lane&15)*8)
// 16B fp16x8 gathers, 4 edges/issue, 16 edges in flight; butterfly reduce.
__global__ __launch_bounds__(256) void aggregate_w(
    const _Float16* __restrict__ hn, const int* __restrict__ row_ptr,
    const int* __restrict__ esrc, float* __restrict__ pre) {
    int wave = threadIdx.x >> 6, lane = threadIdx.x & 63;
    int n = blockIdx.x * 4 + wave;
    if (n >= N_NODES) return;
    int start = row_ptr[n], end = row_ptr[n + 1];
    int eg = lane >> 4;            // edge slot 0..3
    int c8 = (lane & 15) * 8;      // channel group

    float acc[8] = {};
    for (int base = start; base < end; base += 16) {
        #pragma unroll
        for (int u = 0; u < 4; u++) {
            int e = base + u * 4 + eg;
            if (e < end) {
                int s = esrc[e];
                half8 v = *(const half8*)&hn[(size_t)s * HDIM + c8];
                #pragma unroll
                for (int i = 0; i < 8; i++) acc[i] += (float)v[i];
            }
        }
    }
    // fold edge groups: xor 16, 32
    #pragma unroll
    for (int i = 0; i < 8; i++) {
        acc[i] += __shfl_xor(acc[i], 16, 64);
        acc[i] += __shfl_xor(acc[i], 32, 64);
    }
    if (eg == 0) {
        float rd = 1.0f / (float)max(end - start, 1);
        size_t off = (size_t)n * HDIM + c8;
        float4 p0 = *(float4*)&pre[off];
        float4 p1 = *(float4*)&pre[off + 4];
        p0.x += acc[0] * rd; p0.y += acc[1] * rd;
        p0.z += acc[2] * rd; p0.w += acc[3] * rd;
        p1.x += acc[4] * rd; p1.y += acc[5] * rd;
        p1.z += acc[6] * rd; p1.w += acc[7] * rd;
        *(float4*)&pre[off]     = p0;
        *(float4*)&pre[off + 4] = p1;
    }
}

// --------------------------------------------------------------- batch norm
__global__ void bn_stats(const float* __restrict__ P, float* __restrict__ gsum,
                         float* __restrict__ gsumsq, int M, int C) {
    int tid = threadIdx.x;
    int c = tid % C;
    int rpb = 256 / C;
    float s = 0.0f, s2 = 0.0f;
    for (int r = blockIdx.x * rpb + tid / C; r < M; r += gridDim.x * rpb) {
        float v = P[(size_t)r * C + c];
        s += v; s2 += v * v;
    }
    __shared__ float ss[256], ss2[256];
    ss[tid] = s; ss2[tid] = s2;
    __syncthreads();
    for (int off = 128; off >= C; off >>= 1) {
        if (tid < off) { ss[tid] += ss[tid + off]; ss2[tid] += ss2[tid + off]; }
        __syncthreads();
    }
    if (tid < C) {
        atomicAdd(&gsum[tid], ss[tid]);
        atomicAdd(&gsumsq[tid], ss2[tid]);
    }
}

__global__ void bn_finalize(const float* __restrict__ gsum, const float* __restrict__ gsumsq,
                            const float* __restrict__ gamma, const float* __restrict__ beta,
                            float* __restrict__ scale, float* __restrict__ shift,
                            int M, int C) {
    int c = threadIdx.x;
    if (c < C) {
        float mean = gsum[c] / (float)M;
        float var = gsumsq[c] / (float)M - mean * mean;
        float sc = rsqrtf(var + 1e-5f) * gamma[c];
        scale[c] = sc;
        shift[c] = beta[c] - mean * sc;
    }
}

__global__ void bn_apply(const float* __restrict__ P, const float* __restrict__ res,
                         float* __restrict__ out, _Float16* __restrict__ out16,
                         const float* __restrict__ scale, const float* __restrict__ shift,
                         int total4, int Cdiv4) {
    for (int f = blockIdx.x * blockDim.x + threadIdx.x; f < total4;
         f += gridDim.x * blockDim.x) {
        int c4 = (f % Cdiv4) * 4;
        float4 v = ((const float4*)P)[f];
        v.x = v.x * scale[c4 + 0] + shift[c4 + 0];
        v.y = v.y * scale[c4 + 1] + shift[c4 + 1];
        v.z = v.z * scale[c4 + 2] + shift[c4 + 2];
        v.w = v.w * scale[c4 + 3] + shift[c4 + 3];
        if (res) {
            float4 rv = ((const float4*)res)[f];
            v.x += rv.x; v.y += rv.y; v.z += rv.z; v.w += rv.w;
        }
        v.x = fmaxf(v.x, 0.0f); v.y = fmaxf(v.y, 0.0f);
        v.z = fmaxf(v.z, 0.0f); v.w = fmaxf(v.w, 0.0f);
        ((float4*)out)[f] = v;
        if (out16) {
            half4 h;
            h[0] = (_Float16)v.x; h[1] = (_Float16)v.y;
            h[2] = (_Float16)v.z; h[3] = (_Float16)v.w;
            *(half4*)&out16[(size_t)f * 4] = h;
        }
    }
}

// --------------------------------------------------------------- MLP head
// Z = H16(Mx128) @ W1(128x64) + b1   (fp32 math, fp16 activations)
__global__ __launch_bounds__(256) void mlp_gemm(const _Float16* __restrict__ H,
                                                const float* __restrict__ W1,
                                                const float* __restrict__ b1,
                                                float* __restrict__ Z, int M) {
    __shared__ float hs[64 * 132];
    __shared__ float ws[128 * 64];
    int tid = threadIdx.x;
    int tx = tid & 15;
    int ty = tid >> 4;
    int row0 = blockIdx.x * 64;

    #pragma unroll
    for (int t = 0; t < 8; t++) {
        int f = tid + t * 256;
        int r = f >> 4, c4 = (f & 15) * 4;
        *(float4*)&ws[r * 64 + c4] = *(const float4*)&W1[r * 64 + c4];
    }
    #pragma unroll
    for (int t = 0; t < 4; t++) {           // H tile: 64x128 halves = 1024 chunks of 8
        int f = tid + t * 256;
        int r = f >> 4, c8 = (f & 15) * 8;
        int gr = row0 + r;
        if (gr < M) {
            half8 hv = *(const half8*)&H[(size_t)gr * HDIM + c8];
            #pragma unroll
            for (int i = 0; i < 8; i++) hs[r * 132 + c8 + i] = (float)hv[i];
        } else {
            #pragma unroll
            for (int i = 0; i < 8; i++) hs[r * 132 + c8 + i] = 0.0f;
        }
    }
    __syncthreads();

    float acc[4][4] = {};
    for (int k = 0; k < 128; k++) {
        float a[4];
        #pragma unroll
        for (int i = 0; i < 4; i++) a[i] = hs[(ty * 4 + i) * 132 + k];
        float4 b4 = *(const float4*)&ws[k * 64 + tx * 4];
        #pragma unroll
        for (int i = 0; i < 4; i++) {
            acc[i][0] += a[i] * b4.x; acc[i][1] += a[i] * b4.y;
            acc[i][2] += a[i] * b4.z; acc[i][3] += a[i] * b4.w;
        }
    }
    float4 bb = *(const float4*)&b1[tx * 4];
    #pragma unroll
    for (int i = 0; i < 4; i++) {
        int r = row0 + ty * 4 + i;
        if (r < M) {
            float4 v = {acc[i][0] + bb.x, acc[i][1] + bb.y,
                        acc[i][2] + bb.z, acc[i][3] + bb.w};
            *(float4*)&Z[(size_t)r * 64 + tx * 4] = v;
        }
    }
}

__global__ void final_out(const float* __restrict__ Z, const float* __restrict__ W2,
                          const float* __restrict__ b2, float* __restrict__ out) {
    int t = blockIdx.x * blockDim.x + threadIdx.x;
    int n = t >> 6;
    int lane = t & 63;
    if (n >= N_NODES) return;
    float v = Z[(size_t)n * 64 + lane] * W2[lane];
    #pragma unroll
    for (int off = 32; off >= 1; off >>= 1) v += __shfl_down(v, off, 64);
    if (lane == 0) out[n] = v + b2[0];
}

// ------------------------------------------------------------------ driver
extern "C" void kernel_launch(void* const* d_in, const int* in_sizes, int n_in,
                              void* d_out, int out_size, void* d_ws, size_t ws_size,
                              hipStream_t stream) {
    const float* X       = (const float*)d_in[0];
    const int*   graph   = (const int*)d_in[1];
    const float* Wself0  = (const float*)d_in[2];
    const float* Wneigh0 = (const float*)d_in[3];
    const float* b0      = (const float*)d_in[4];
    const float* Wself   = (const float*)d_in[5];
    const float* Wneigh  = (const float*)d_in[6];
    const float* bvec    = (const float*)d_in[7];
    const float* bn_g    = (const float*)d_in[8];
    const float* bn_b    = (const float*)d_in[9];
    const float* W1      = (const float*)d_in[10];
    const float* b1      = (const float*)d_in[11];
    const float* bng1    = (const float*)d_in[12];
    const float* bnb1    = (const float*)d_in[13];
    const float* W2      = (const float*)d_in[14];
    const float* b2      = (const float*)d_in[15];
    float* out = (float*)d_out;

    size_t off = 0;
    auto alloc = [&](size_t bytes) {
        void* p = (char*)d_ws + off;
        off += (bytes + 255) & ~(size_t)255;
        return p;
    };
    int* cnt     = (int*)alloc(N_NODES * 4);
    int* cursor  = (int*)alloc(N_NODES * 4);
    int* row_ptr = (int*)alloc((N_NODES + 1) * 4);
    int* incl    = (int*)alloc(N_NODES * 4);
    int* blk     = (int*)alloc(NB_SCAN * 4);
    int* blkoff  = (int*)alloc(NB_SCAN * 4);
    int* esrc    = (int*)alloc((size_t)N_EDGES * 4);
    char* xh_region = (char*)alloc((size_t)N_NODES * KPAD0 * 2);   // 140.8 MB
    _Float16* Xh  = (_Float16*)xh_region;
    float*    hA  = (float*)xh_region;                              // 51.2 MB
    _Float16* h16 = (_Float16*)(xh_region + (size_t)N_NODES * HDIM * 4);
    float*    Z   = (float*)(xh_region + (size_t)N_NODES * HDIM * 6);
    float*    hB  = (float*)alloc((size_t)N_NODES * HDIM * 4);
    _Float16* hn16 = (_Float16*)alloc((size_t)N_NODES * HDIM * 2);
    _Float16* Wtp0 = (_Float16*)alloc((size_t)NKB0 * 8192 * 2);
    _Float16* Wtpl = (_Float16*)alloc((size_t)3 * 4 * 8192 * 2);
    float* stats = (float*)alloc(512 * 4);
    float* gsum = stats, *gsumsq = stats + 128, *scale = stats + 256, *shift = stats + 384;

    const int EB = (N_EDGES + 255) / 256;
    const int GB = (N_NODES + GBM - 1) / GBM;   // 782
    const int AGB = (N_NODES + 3) / 4;          // 25000

    // CSR build
    hipMemsetAsync(cnt, 0, N_NODES * 4, stream);
    hipMemsetAsync(cursor, 0, N_NODES * 4, stream);
    count_edges<<<EB, 256, 0, stream>>>(graph, cnt);
    scan1<<<NB_SCAN, SCAN_B, 0, stream>>>(cnt, incl, blk);
    scan2<<<1, 512, 0, stream>>>(blk, blkoff);
    scan3<<<NB_SCAN, SCAN_B, 0, stream>>>(incl, blkoff, row_ptr);
    fill_edges<<<EB, 256, 0, stream>>>(graph, row_ptr, cursor, esrc);

    // weight packs + X conversion
    build_wtp0<<<(NKB0 * 1024 + 255) / 256, 256, 0, stream>>>(Wneigh0, Wself0, Wtp0);
    build_wtpl<<<(3 * 4096 + 255) / 256, 256, 0, stream>>>(Wneigh, Wself, Wtpl);
    convert_x<<<2048, 256, 0, stream>>>(X, Xh);

    float* h   = hA;
    float* pre = hB;

    // ---- layer 0 (Kpad = 704)
    dual_gemm_mfma<<<GB, 256, 0, stream>>>(Xh, N_NODES, KPAD0, NKB0, Wtp0, b0, hn16, pre);
    aggregate_w<<<AGB, 256, 0, stream>>>(hn16, row_ptr, esrc, pre);
    hipMemsetAsync(stats, 0, 256 * 4, stream);
    bn_stats<<<512, 256, 0, stream>>>(pre, gsum, gsumsq, N_NODES, 128);
    bn_finalize<<<1, 128, 0, stream>>>(gsum, gsumsq, bn_g, bn_b, scale, shift, N_NODES, 128);
    bn_apply<<<1024, 256, 0, stream>>>(pre, nullptr, h, h16, scale, shift,
                                       N_NODES * HDIM / 4, HDIM / 4);

    // ---- layers 1..3 (Kpad = 128, residual)
    for (int l = 0; l < 3; l++) {
        dual_gemm_mfma<<<GB, 256, 0, stream>>>(h16, N_NODES, HDIM, 4,
                                               Wtpl + (size_t)l * 32768,
                                               bvec + l * HDIM, hn16, pre);
        aggregate_w<<<AGB, 256, 0, stream>>>(hn16, row_ptr, esrc, pre);
        hipMemsetAsync(stats, 0, 256 * 4, stream);
        bn_stats<<<512, 256, 0, stream>>>(pre, gsum, gsumsq, N_NODES, 128);
        bn_finalize<<<1, 128, 0, stream>>>(gsum, gsumsq, bn_g + (l + 1) * HDIM,
                                           bn_b + (l + 1) * HDIM, scale, shift,
                                           N_NODES, 128);
        bn_apply<<<1024, 256, 0, stream>>>(pre, h, pre, h16, scale, shift,
                                           N_NODES * HDIM / 4, HDIM / 4);
        float* t = h; h = pre; pre = t;
    }

    // ---- MLP head
    mlp_gemm<<<(N_NODES + 63) / 64, 256, 0, stream>>>(h16, W1, b1, Z, N_NODES);
    hipMemsetAsync(stats, 0, 256 * 4, stream);
    bn_stats<<<512, 256, 0, stream>>>(Z, gsum, gsumsq, N_NODES, 64);
    bn_finalize<<<1, 64, 0, stream>>>(gsum, gsumsq, bng1, bnb1, scale, shift, N_NODES, 64);
    bn_apply<<<1024, 256, 0, stream>>>(Z, nullptr, Z, nullptr, scale, shift,
                                       N_NODES * 64 / 4, 64 / 4);
    final_out<<<(N_NODES * 64) / 256, 256, 0, stream>>>(Z, W2, b2, out);
}

// Round 5
// 1536.575 us; speedup vs baseline: 1.4329x; 1.0417x over previous
//
#include <hip/hip_runtime.h>
#include <hip/hip_bf16.h>

#define N_NODES 100000
#define N_EDGES 1600000
#define F_IN    700
#define NKB0    22          // ceil(700/32)
#define HDIM    128
#define SCAN_B  256
#define NB_SCAN ((N_NODES + SCAN_B - 1) / SCAN_B)   // 391

typedef _Float16 half8 __attribute__((ext_vector_type(8)));
typedef _Float16 half4 __attribute__((ext_vector_type(4)));
typedef float floatx4 __attribute__((ext_vector_type(4)));

// async global->LDS, 16B per lane; dst slot = wave-uniform base + lane*16
__device__ __forceinline__ void cp16(const void* g, void* l) {
    __builtin_amdgcn_global_load_lds(
        (const __attribute__((address_space(1))) void*)g,
        (__attribute__((address_space(3))) void*)l, 16, 0, 0);
}

// ---------------------------------------------------------------- CSR build
__global__ void count_edges(const int* __restrict__ graph, int* __restrict__ cnt) {
    int e = blockIdx.x * blockDim.x + threadIdx.x;
    if (e < N_EDGES) atomicAdd(&cnt[graph[2 * e + 1]], 1);
}

__global__ void scan1(const int* __restrict__ cnt, int* __restrict__ incl,
                      int* __restrict__ blk) {
    __shared__ int s[SCAN_B];
    int tid = threadIdx.x;
    int i = blockIdx.x * SCAN_B + tid;
    s[tid] = (i < N_NODES) ? cnt[i] : 0;
    __syncthreads();
    for (int off = 1; off < SCAN_B; off <<= 1) {
        int t = (tid >= off) ? s[tid - off] : 0;
        __syncthreads();
        s[tid] += t;
        __syncthreads();
    }
    if (i < N_NODES) incl[i] = s[tid];
    if (tid == SCAN_B - 1) blk[blockIdx.x] = s[tid];
}

__global__ void scan2(const int* __restrict__ blk, int* __restrict__ blkoff) {
    __shared__ int s[512];
    int tid = threadIdx.x;
    s[tid] = (tid < NB_SCAN) ? blk[tid] : 0;
    __syncthreads();
    for (int off = 1; off < 512; off <<= 1) {
        int t = (tid >= off) ? s[tid - off] : 0;
        __syncthreads();
        s[tid] += t;
        __syncthreads();
    }
    if (tid < NB_SCAN) blkoff[tid] = (tid == 0) ? 0 : s[tid - 1];
}

__global__ void scan3(const int* __restrict__ incl, const int* __restrict__ blkoff,
                      int* __restrict__ row_ptr) {
    int i = blockIdx.x * SCAN_B + threadIdx.x;
    if (i < N_NODES) {
        row_ptr[i + 1] = incl[i] + blkoff[i >> 8];
        if (i == 0) row_ptr[0] = 0;
    }
}

__global__ void fill_edges(const int* __restrict__ graph, const int* __restrict__ row_ptr,
                           int* __restrict__ cursor, int* __restrict__ esrc) {
    int e = blockIdx.x * blockDim.x + threadIdx.x;
    if (e < N_EDGES) {
        int src = graph[2 * e];
        int dst = graph[2 * e + 1];
        esrc[row_ptr[dst] + atomicAdd(&cursor[dst], 1)] = src;
    }
}

// ------------------- weight packs: tile-major, XOR-swizzled LDS image (fp16)
__global__ void build_wtp0(const float* __restrict__ Wn, const float* __restrict__ Ws,
                           _Float16* __restrict__ out) {
    int q = blockIdx.x * blockDim.x + threadIdx.x;
    if (q >= NKB0 * 256 * 4) return;
    int kb = q >> 10;
    int r  = (q >> 2) & 255;
    int cc = q & 3;
    int k0 = kb * 32 + (cc ^ ((r >> 1) & 3)) * 8;
    half8 v;
    #pragma unroll
    for (int e = 0; e < 8; e++) {
        int k = k0 + e;
        float f = 0.0f;
        if (k < F_IN) f = (r < 128) ? Wn[k * 128 + r] : Ws[k * 128 + (r - 128)];
        v[e] = (_Float16)f;
    }
    *(half8*)&out[(size_t)q * 8] = v;
}

__global__ void build_wtpl(const float* __restrict__ Wn, const float* __restrict__ Ws,
                           _Float16* __restrict__ out) {
    int q = blockIdx.x * blockDim.x + threadIdx.x;
    if (q >= 3 * 4 * 256 * 4) return;
    int l = q >> 12;
    int rem = q & 4095;
    int kb = rem >> 10;
    int r  = (rem >> 2) & 255;
    int cc = rem & 3;
    int k0 = kb * 32 + (cc ^ ((r >> 1) & 3)) * 8;
    half8 v;
    #pragma unroll
    for (int e = 0; e < 8; e++) {
        int k = k0 + e;
        float f = (r < 128) ? Wn[l * 16384 + k * 128 + r]
                            : Ws[l * 16384 + k * 128 + (r - 128)];
        v[e] = (_Float16)f;
    }
    *(half8*)&out[(size_t)q * 8] = v;
}

// ----------------- layer-0 GEMM: fp32 A staged raw, cvt at frag read
// Cn(fp16) = A @ Wt[0:128]^T ; Cs(fp32) = A @ Wt[128:256]^T + bias
#define GBM 128
__global__ __launch_bounds__(256) void dual_gemm_f32a(
    const float* __restrict__ A, int M, int K, int NKB,
    const _Float16* __restrict__ Wtp, const float* __restrict__ bias,
    const float* __restrict__ zbuf,
    _Float16* __restrict__ Cn, float* __restrict__ Cs) {
    // per buffer: A 128x32 fp32 (16KB) at byte 0, B 256x32 fp16 (16KB) at 16384
    __shared__ char sbuf[2][32768];

    int tid = threadIdx.x;
    int wave = tid >> 6, lane = tid & 63;
    int lm = lane & 15, quad = lane >> 4;
    int wm = wave >> 1, wn = wave & 1;
    long row0 = (long)blockIdx.x * GBM;

    floatx4 acc[4][8] = {};

    auto stage = [&](int kb, char* buf) {
        // A: 1024 16B chunks (4-float), XOR-swizzled: slot cc holds chunk cc^(r&7)
        #pragma unroll
        for (int pass = 0; pass < 4; pass++) {
            int q = pass * 256 + tid;
            int r = q >> 3, cc = q & 7;
            int ccg = cc ^ (r & 7);
            long grow = row0 + r;
            int gk = kb * 32 + ccg * 4;
            const float* src = (gk + 4 <= K) ? (A + grow * (long)K + gk) : zbuf;
            char* dst = buf + pass * 4096 + wave * 1024;
            if (grow < M) cp16(src, dst);
        }
        // B: 1024 chunks, fully linear (pre-swizzled at pack time)
        const _Float16* wsrc = Wtp + (size_t)kb * 8192;
        #pragma unroll
        for (int pass = 0; pass < 4; pass++) {
            cp16(wsrc + (size_t)(pass * 256 + tid) * 8,
                 buf + 16384 + pass * 4096 + wave * 1024);
        }
    };

    stage(0, sbuf[0]);
    __syncthreads();

    for (int kb = 0; kb < NKB; kb++) {
        int p = kb & 1;
        if (kb + 1 < NKB) stage(kb + 1, sbuf[p ^ 1]);

        const float* Af = (const float*)sbuf[p];
        const _Float16* Bf = (const _Float16*)(sbuf[p] + 16384);
        half8 af[4];
        #pragma unroll
        for (int i = 0; i < 4; i++) {
            int row = wm * 64 + i * 16 + lm;
            int c0 = (quad * 2) ^ (row & 7);
            int c1 = (quad * 2 + 1) ^ (row & 7);
            floatx4 f0 = *(const floatx4*)&Af[row * 32 + c0 * 4];
            floatx4 f1 = *(const floatx4*)&Af[row * 32 + c1 * 4];
            af[i][0] = (_Float16)f0[0]; af[i][1] = (_Float16)f0[1];
            af[i][2] = (_Float16)f0[2]; af[i][3] = (_Float16)f0[3];
            af[i][4] = (_Float16)f1[0]; af[i][5] = (_Float16)f1[1];
            af[i][6] = (_Float16)f1[2]; af[i][7] = (_Float16)f1[3];
        }
        #pragma unroll
        for (int j = 0; j < 8; j++) {
            int brow = wn * 128 + j * 16 + lm;
            int ch = quad ^ ((brow >> 1) & 3);
            half8 bf = *(const half8*)&Bf[brow * 32 + ch * 8];
            #pragma unroll
            for (int i = 0; i < 4; i++)
                acc[i][j] = __builtin_amdgcn_mfma_f32_16x16x32_f16(af[i], bf, acc[i][j], 0, 0, 0);
        }
        __syncthreads();
    }

    #pragma unroll
    for (int i = 0; i < 4; i++) {
        long r0 = row0 + wm * 64 + i * 16 + quad * 4;
        #pragma unroll
        for (int j = 0; j < 8; j++) {
            int c = j * 16 + lm;
            if (wn) {
                float badd = bias[c];
                #pragma unroll
                for (int rr = 0; rr < 4; rr++) {
                    long r = r0 + rr;
                    if (r < M) Cs[r * HDIM + c] = acc[i][j][rr] + badd;
                }
            } else {
                #pragma unroll
                for (int rr = 0; rr < 4; rr++) {
                    long r = r0 + rr;
                    if (r < M) Cn[r * HDIM + c] = (_Float16)acc[i][j][rr];
                }
            }
        }
    }
}

// -------------------------- K=128 layers: fp16 A, async + dbuf (unchanged)
__global__ __launch_bounds__(256) void dual_gemm_mfma(
    const _Float16* __restrict__ A, int M, int Kpad, int NKB,
    const _Float16* __restrict__ Wtp, const float* __restrict__ bias,
    _Float16* __restrict__ Cn, float* __restrict__ Cs) {
    __shared__ _Float16 sbuf[2][12288];

    int tid = threadIdx.x;
    int wave = tid >> 6, lane = tid & 63;
    int lm = lane & 15, quad = lane >> 4;
    int wm = wave >> 1, wn = wave & 1;
    long row0 = (long)blockIdx.x * GBM;

    floatx4 acc[4][8] = {};

    auto stage = [&](int kb, _Float16* buf) {
        #pragma unroll
        for (int pass = 0; pass < 2; pass++) {
            int q = pass * 256 + tid;
            int r = q >> 2, cc = q & 3;
            int ccg = cc ^ ((r >> 1) & 3);
            long grow = row0 + r;
            _Float16* dst = buf + pass * 2048 + wave * 512;
            if (grow < M)
                cp16(A + grow * (long)Kpad + kb * 32 + ccg * 8, dst);
        }
        const _Float16* wsrc = Wtp + (size_t)kb * 8192;
        #pragma unroll
        for (int pass = 0; pass < 4; pass++) {
            cp16(wsrc + (size_t)(pass * 256 + tid) * 8,
                 buf + 4096 + pass * 2048 + wave * 512);
        }
    };

    stage(0, sbuf[0]);
    __syncthreads();

    for (int kb = 0; kb < NKB; kb++) {
        int p = kb & 1;
        if (kb + 1 < NKB) stage(kb + 1, sbuf[p ^ 1]);

        const _Float16* bp = sbuf[p];
        half8 af[4];
        #pragma unroll
        for (int i = 0; i < 4; i++) {
            int row = wm * 64 + i * 16 + lm;
            int ch = quad ^ ((row >> 1) & 3);
            af[i] = *(const half8*)&bp[row * 32 + ch * 8];
        }
        #pragma unroll
        for (int j = 0; j < 8; j++) {
            int brow = wn * 128 + j * 16 + lm;
            int ch = quad ^ ((brow >> 1) & 3);
            half8 bf = *(const half8*)&bp[4096 + brow * 32 + ch * 8];
            #pragma unroll
            for (int i = 0; i < 4; i++)
                acc[i][j] = __builtin_amdgcn_mfma_f32_16x16x32_f16(af[i], bf, acc[i][j], 0, 0, 0);
        }
        __syncthreads();
    }

    #pragma unroll
    for (int i = 0; i < 4; i++) {
        long r0 = row0 + wm * 64 + i * 16 + quad * 4;
        #pragma unroll
        for (int j = 0; j < 8; j++) {
            int c = j * 16 + lm;
            if (wn) {
                float badd = bias[c];
                #pragma unroll
                for (int rr = 0; rr < 4; rr++) {
                    long r = r0 + rr;
                    if (r < M) Cs[r * HDIM + c] = acc[i][j][rr] + badd;
                }
            } else {
                #pragma unroll
                for (int rr = 0; rr < 4; rr++) {
                    long r = r0 + rr;
                    if (r < M) Cn[r * HDIM + c] = (_Float16)acc[i][j][rr];
                }
            }
        }
    }
}

// ------------------------------------------------------------- aggregation
__global__ __launch_bounds__(256) void aggregate_w(
    const _Float16* __restrict__ hn, const int* __restrict__ row_ptr,
    const int* __restrict__ esrc, float* __restrict__ pre) {
    int wave = threadIdx.x >> 6, lane = threadIdx.x & 63;
    int n = blockIdx.x * 4 + wave;
    if (n >= N_NODES) return;
    int start = row_ptr[n], end = row_ptr[n + 1];
    int eg = lane >> 4;            // edge slot 0..3
    int c8 = (lane & 15) * 8;      // channel group

    float acc[8] = {};
    for (int base = start; base < end; base += 16) {
        #pragma unroll
        for (int u = 0; u < 4; u++) {
            int e = base + u * 4 + eg;
            if (e < end) {
                int s = esrc[e];
                half8 v = *(const half8*)&hn[(size_t)s * HDIM + c8];
                #pragma unroll
                for (int i = 0; i < 8; i++) acc[i] += (float)v[i];
            }
        }
    }
    #pragma unroll
    for (int i = 0; i < 8; i++) {
        acc[i] += __shfl_xor(acc[i], 16, 64);
        acc[i] += __shfl_xor(acc[i], 32, 64);
    }
    if (eg == 0) {
        float rd = 1.0f / (float)max(end - start, 1);
        size_t off = (size_t)n * HDIM + c8;
        float4 p0 = *(float4*)&pre[off];
        float4 p1 = *(float4*)&pre[off + 4];
        p0.x += acc[0] * rd; p0.y += acc[1] * rd;
        p0.z += acc[2] * rd; p0.w += acc[3] * rd;
        p1.x += acc[4] * rd; p1.y += acc[5] * rd;
        p1.z += acc[6] * rd; p1.w += acc[7] * rd;
        *(float4*)&pre[off]     = p0;
        *(float4*)&pre[off + 4] = p1;
    }
}

// --------------------------------------------------------------- batch norm
__global__ void bn_stats(const float* __restrict__ P, float* __restrict__ gsum,
                         float* __restrict__ gsumsq, int M, int C) {
    int tid = threadIdx.x;
    int c = tid % C;
    int rpb = 256 / C;
    float s = 0.0f, s2 = 0.0f;
    for (int r = blockIdx.x * rpb + tid / C; r < M; r += gridDim.x * rpb) {
        float v = P[(size_t)r * C + c];
        s += v; s2 += v * v;
    }
    __shared__ float ss[256], ss2[256];
    ss[tid] = s; ss2[tid] = s2;
    __syncthreads();
    for (int off = 128; off >= C; off >>= 1) {
        if (tid < off) { ss[tid] += ss[tid + off]; ss2[tid] += ss2[tid + off]; }
        __syncthreads();
    }
    if (tid < C) {
        atomicAdd(&gsum[tid], ss[tid]);
        atomicAdd(&gsumsq[tid], ss2[tid]);
    }
}

__global__ void bn_finalize(const float* __restrict__ gsum, const float* __restrict__ gsumsq,
                            const float* __restrict__ gamma, const float* __restrict__ beta,
                            float* __restrict__ scale, float* __restrict__ shift,
                            int M, int C) {
    int c = threadIdx.x;
    if (c < C) {
        float mean = gsum[c] / (float)M;
        float var = gsumsq[c] / (float)M - mean * mean;
        float sc = rsqrtf(var + 1e-5f) * gamma[c];
        scale[c] = sc;
        shift[c] = beta[c] - mean * sc;
    }
}

// h16 = fp16( relu(P*scale+shift [+ res16]) )   — fp32 math, fp16 storage
__global__ void bn_apply16(const float* __restrict__ P, const _Float16* __restrict__ res16,
                           _Float16* __restrict__ out16,
                           const float* __restrict__ scale, const float* __restrict__ shift,
                           int total4, int Cdiv4) {
    for (int f = blockIdx.x * blockDim.x + threadIdx.x; f < total4;
         f += gridDim.x * blockDim.x) {
        int c4 = (f % Cdiv4) * 4;
        float4 v = ((const float4*)P)[f];
        v.x = v.x * scale[c4 + 0] + shift[c4 + 0];
        v.y = v.y * scale[c4 + 1] + shift[c4 + 1];
        v.z = v.z * scale[c4 + 2] + shift[c4 + 2];
        v.w = v.w * scale[c4 + 3] + shift[c4 + 3];
        if (res16) {
            half4 rv = *(const half4*)&res16[(size_t)f * 4];
            v.x += (float)rv[0]; v.y += (float)rv[1];
            v.z += (float)rv[2]; v.w += (float)rv[3];
        }
        half4 h;
        h[0] = (_Float16)fmaxf(v.x, 0.0f); h[1] = (_Float16)fmaxf(v.y, 0.0f);
        h[2] = (_Float16)fmaxf(v.z, 0.0f); h[3] = (_Float16)fmaxf(v.w, 0.0f);
        *(half4*)&out16[(size_t)f * 4] = h;
    }
}

// --------------------------------------------------------------- MLP head
__global__ __launch_bounds__(256) void mlp_gemm(const _Float16* __restrict__ H,
                                                const float* __restrict__ W1,
                                                const float* __restrict__ b1,
                                                float* __restrict__ Z, int M) {
    __shared__ float hs[64 * 132];
    __shared__ float ws[128 * 64];
    int tid = threadIdx.x;
    int tx = tid & 15;
    int ty = tid >> 4;
    int row0 = blockIdx.x * 64;

    #pragma unroll
    for (int t = 0; t < 8; t++) {
        int f = tid + t * 256;
        int r = f >> 4, c4 = (f & 15) * 4;
        *(float4*)&ws[r * 64 + c4] = *(const float4*)&W1[r * 64 + c4];
    }
    #pragma unroll
    for (int t = 0; t < 4; t++) {
        int f = tid + t * 256;
        int r = f >> 4, c8 = (f & 15) * 8;
        int gr = row0 + r;
        if (gr < M) {
            half8 hv = *(const half8*)&H[(size_t)gr * HDIM + c8];
            #pragma unroll
            for (int i = 0; i < 8; i++) hs[r * 132 + c8 + i] = (float)hv[i];
        } else {
            #pragma unroll
            for (int i = 0; i < 8; i++) hs[r * 132 + c8 + i] = 0.0f;
        }
    }
    __syncthreads();

    float acc[4][4] = {};
    for (int k = 0; k < 128; k++) {
        float a[4];
        #pragma unroll
        for (int i = 0; i < 4; i++) a[i] = hs[(ty * 4 + i) * 132 + k];
        float4 b4 = *(const float4*)&ws[k * 64 + tx * 4];
        #pragma unroll
        for (int i = 0; i < 4; i++) {
            acc[i][0] += a[i] * b4.x; acc[i][1] += a[i] * b4.y;
            acc[i][2] += a[i] * b4.z; acc[i][3] += a[i] * b4.w;
        }
    }
    float4 bb = *(const float4*)&b1[tx * 4];
    #pragma unroll
    for (int i = 0; i < 4; i++) {
        int r = row0 + ty * 4 + i;
        if (r < M) {
            float4 v = {acc[i][0] + bb.x, acc[i][1] + bb.y,
                        acc[i][2] + bb.z, acc[i][3] + bb.w};
            *(float4*)&Z[(size_t)r * 64 + tx * 4] = v;
        }
    }
}

// out[n] = relu(bn(Z[n,:])) . W2 + b2  — BN apply fused into the dot
__global__ void final_out(const float* __restrict__ Z,
                          const float* __restrict__ scale, const float* __restrict__ shift,
                          const float* __restrict__ W2, const float* __restrict__ b2,
                          float* __restrict__ out) {
    int t = blockIdx.x * blockDim.x + threadIdx.x;
    int n = t >> 6;
    int lane = t & 63;
    if (n >= N_NODES) return;
    float z = Z[(size_t)n * 64 + lane] * scale[lane] + shift[lane];
    z = fmaxf(z, 0.0f);
    float v = z * W2[lane];
    #pragma unroll
    for (int off = 32; off >= 1; off >>= 1) v += __shfl_down(v, off, 64);
    if (lane == 0) out[n] = v + b2[0];
}

// ------------------------------------------------------------------ driver
extern "C" void kernel_launch(void* const* d_in, const int* in_sizes, int n_in,
                              void* d_out, int out_size, void* d_ws, size_t ws_size,
                              hipStream_t stream) {
    const float* X       = (const float*)d_in[0];
    const int*   graph   = (const int*)d_in[1];
    const float* Wself0  = (const float*)d_in[2];
    const float* Wneigh0 = (const float*)d_in[3];
    const float* b0      = (const float*)d_in[4];
    const float* Wself   = (const float*)d_in[5];
    const float* Wneigh  = (const float*)d_in[6];
    const float* bvec    = (const float*)d_in[7];
    const float* bn_g    = (const float*)d_in[8];
    const float* bn_b    = (const float*)d_in[9];
    const float* W1      = (const float*)d_in[10];
    const float* b1      = (const float*)d_in[11];
    const float* bng1    = (const float*)d_in[12];
    const float* bnb1    = (const float*)d_in[13];
    const float* W2      = (const float*)d_in[14];
    const float* b2      = (const float*)d_in[15];
    float* out = (float*)d_out;

    size_t off = 0;
    auto alloc = [&](size_t bytes) {
        void* p = (char*)d_ws + off;
        off += (bytes + 255) & ~(size_t)255;
        return p;
    };
    int* cnt     = (int*)alloc(N_NODES * 4);
    int* cursor  = (int*)alloc(N_NODES * 4);
    int* row_ptr = (int*)alloc((N_NODES + 1) * 4);
    int* incl    = (int*)alloc(N_NODES * 4);
    int* blk     = (int*)alloc(NB_SCAN * 4);
    int* blkoff  = (int*)alloc(NB_SCAN * 4);
    int* esrc    = (int*)alloc((size_t)N_EDGES * 4);
    float*    pre   = (float*)alloc((size_t)N_NODES * HDIM * 4);    // 51.2 MB
    _Float16* h16A  = (_Float16*)alloc((size_t)N_NODES * HDIM * 2); // 25.6 MB
    _Float16* h16B  = (_Float16*)alloc((size_t)N_NODES * HDIM * 2);
    _Float16* hn16  = (_Float16*)alloc((size_t)N_NODES * HDIM * 2);
    float*    Z     = (float*)alloc((size_t)N_NODES * 64 * 4);
    _Float16* Wtp0  = (_Float16*)alloc((size_t)NKB0 * 8192 * 2);
    _Float16* Wtpl  = (_Float16*)alloc((size_t)3 * 4 * 8192 * 2);
    float*    zbuf  = (float*)alloc(256);
    float* stats = (float*)alloc(512 * 4);
    float* gsum = stats, *gsumsq = stats + 128, *scale = stats + 256, *shift = stats + 384;

    const int EB = (N_EDGES + 255) / 256;
    const int GB = (N_NODES + GBM - 1) / GBM;   // 782
    const int AGB = (N_NODES + 3) / 4;          // 25000

    // CSR build
    hipMemsetAsync(cnt, 0, N_NODES * 4, stream);
    hipMemsetAsync(cursor, 0, N_NODES * 4, stream);
    hipMemsetAsync(zbuf, 0, 256, stream);
    count_edges<<<EB, 256, 0, stream>>>(graph, cnt);
    scan1<<<NB_SCAN, SCAN_B, 0, stream>>>(cnt, incl, blk);
    scan2<<<1, 512, 0, stream>>>(blk, blkoff);
    scan3<<<NB_SCAN, SCAN_B, 0, stream>>>(incl, blkoff, row_ptr);
    fill_edges<<<EB, 256, 0, stream>>>(graph, row_ptr, cursor, esrc);

    // weight packs
    build_wtp0<<<(NKB0 * 1024 + 255) / 256, 256, 0, stream>>>(Wneigh0, Wself0, Wtp0);
    build_wtpl<<<(3 * 4096 + 255) / 256, 256, 0, stream>>>(Wneigh, Wself, Wtpl);

    _Float16* hc = h16A;
    _Float16* hx = h16B;

    // ---- layer 0 (K = 700, fp32 A direct)
    dual_gemm_f32a<<<GB, 256, 0, stream>>>(X, N_NODES, F_IN, NKB0, Wtp0, b0, zbuf,
                                           hn16, pre);
    aggregate_w<<<AGB, 256, 0, stream>>>(hn16, row_ptr, esrc, pre);
    hipMemsetAsync(stats, 0, 256 * 4, stream);
    bn_stats<<<512, 256, 0, stream>>>(pre, gsum, gsumsq, N_NODES, 128);
    bn_finalize<<<1, 128, 0, stream>>>(gsum, gsumsq, bn_g, bn_b, scale, shift, N_NODES, 128);
    bn_apply16<<<1024, 256, 0, stream>>>(pre, nullptr, hc, scale, shift,
                                         N_NODES * HDIM / 4, HDIM / 4);

    // ---- layers 1..3 (K = 128, residual in fp16)
    for (int l = 0; l < 3; l++) {
        dual_gemm_mfma<<<GB, 256, 0, stream>>>(hc, N_NODES, HDIM, 4,
                                               Wtpl + (size_t)l * 32768,
                                               bvec + l * HDIM, hn16, pre);
        aggregate_w<<<AGB, 256, 0, stream>>>(hn16, row_ptr, esrc, pre);
        hipMemsetAsync(stats, 0, 256 * 4, stream);
        bn_stats<<<512, 256, 0, stream>>>(pre, gsum, gsumsq, N_NODES, 128);
        bn_finalize<<<1, 128, 0, stream>>>(gsum, gsumsq, bn_g + (l + 1) * HDIM,
                                           bn_b + (l + 1) * HDIM, scale, shift,
                                           N_NODES, 128);
        bn_apply16<<<1024, 256, 0, stream>>>(pre, hc, hx, scale, shift,
                                             N_NODES * HDIM / 4, HDIM / 4);
        _Float16* t = hc; hc = hx; hx = t;
    }

    // ---- MLP head (BN apply + ReLU fused into final_out)
    mlp_gemm<<<(N_NODES + 63) / 64, 256, 0, stream>>>(hc, W1, b1, Z, N_NODES);
    hipMemsetAsync(stats, 0, 256 * 4, stream);
    bn_stats<<<512, 256, 0, stream>>>(Z, gsum, gsumsq, N_NODES, 64);
    bn_finalize<<<1, 64, 0, stream>>>(gsum, gsumsq, bng1, bnb1, scale, shift, N_NODES, 64);
    final_out<<<(N_NODES * 64) / 256, 256, 0, stream>>>(Z, scale, shift, W2, b2, out);
}

// Round 6
// 1328.008 us; speedup vs baseline: 1.6580x; 1.1571x over previous
//
#include <hip/hip_runtime.h>
#include <hip/hip_bf16.h>

#define N_NODES 100000
#define N_EDGES 1600000
#define F_IN    700
#define NKB0    22          // ceil(700/32)
#define HDIM    128
#define SCAN_B  256
#define NB_SCAN ((N_NODES + SCAN_B - 1) / SCAN_B)   // 391

typedef _Float16 half8 __attribute__((ext_vector_type(8)));
typedef _Float16 half4 __attribute__((ext_vector_type(4)));
typedef float floatx4 __attribute__((ext_vector_type(4)));

// async global->LDS, 16B per lane; dst slot = wave-uniform base + lane*16
__device__ __forceinline__ void cp16(const void* g, void* l) {
    __builtin_amdgcn_global_load_lds(
        (const __attribute__((address_space(1))) void*)g,
        (__attribute__((address_space(3))) void*)l, 16, 0, 0);
}

// ---------------------------------------------------------------- CSR build
__global__ void count_edges(const int* __restrict__ graph, int* __restrict__ cnt) {
    int e = blockIdx.x * blockDim.x + threadIdx.x;
    if (e < N_EDGES) atomicAdd(&cnt[graph[2 * e + 1]], 1);
}

__global__ void scan1(const int* __restrict__ cnt, int* __restrict__ incl,
                      int* __restrict__ blk) {
    __shared__ int s[SCAN_B];
    int tid = threadIdx.x;
    int i = blockIdx.x * SCAN_B + tid;
    s[tid] = (i < N_NODES) ? cnt[i] : 0;
    __syncthreads();
    for (int off = 1; off < SCAN_B; off <<= 1) {
        int t = (tid >= off) ? s[tid - off] : 0;
        __syncthreads();
        s[tid] += t;
        __syncthreads();
    }
    if (i < N_NODES) incl[i] = s[tid];
    if (tid == SCAN_B - 1) blk[blockIdx.x] = s[tid];
}

__global__ void scan2(const int* __restrict__ blk, int* __restrict__ blkoff) {
    __shared__ int s[512];
    int tid = threadIdx.x;
    s[tid] = (tid < NB_SCAN) ? blk[tid] : 0;
    __syncthreads();
    for (int off = 1; off < 512; off <<= 1) {
        int t = (tid >= off) ? s[tid - off] : 0;
        __syncthreads();
        s[tid] += t;
        __syncthreads();
    }
    if (tid < NB_SCAN) blkoff[tid] = (tid == 0) ? 0 : s[tid - 1];
}

__global__ void scan3(const int* __restrict__ incl, const int* __restrict__ blkoff,
                      int* __restrict__ row_ptr) {
    int i = blockIdx.x * SCAN_B + threadIdx.x;
    if (i < N_NODES) {
        row_ptr[i + 1] = incl[i] + blkoff[i >> 8];
        if (i == 0) row_ptr[0] = 0;
    }
}

__global__ void fill_edges(const int* __restrict__ graph, const int* __restrict__ row_ptr,
                           int* __restrict__ cursor, int* __restrict__ esrc) {
    int e = blockIdx.x * blockDim.x + threadIdx.x;
    if (e < N_EDGES) {
        int src = graph[2 * e];
        int dst = graph[2 * e + 1];
        esrc[row_ptr[dst] + atomicAdd(&cursor[dst], 1)] = src;
    }
}

// ------------------- weight packs: tile-major, XOR-swizzled LDS image (fp16)
// out[((kb*256 + r)*4 + cc)*8 + e] = W[k = kb*32 + (cc^((r>>1)&3))*8 + e][col r]
// rows 0..127 = Wneigh cols, 128..255 = Wself cols; per-kb halves are 4096-half
// contiguous (8KB), so an N-split block can DMA just its half.
__global__ void build_wtp0(const float* __restrict__ Wn, const float* __restrict__ Ws,
                           _Float16* __restrict__ out) {
    int q = blockIdx.x * blockDim.x + threadIdx.x;
    if (q >= NKB0 * 256 * 4) return;
    int kb = q >> 10;
    int r  = (q >> 2) & 255;
    int cc = q & 3;
    int k0 = kb * 32 + (cc ^ ((r >> 1) & 3)) * 8;
    half8 v;
    #pragma unroll
    for (int e = 0; e < 8; e++) {
        int k = k0 + e;
        float f = 0.0f;
        if (k < F_IN) f = (r < 128) ? Wn[k * 128 + r] : Ws[k * 128 + (r - 128)];
        v[e] = (_Float16)f;
    }
    *(half8*)&out[(size_t)q * 8] = v;
}

__global__ void build_wtpl(const float* __restrict__ Wn, const float* __restrict__ Ws,
                           _Float16* __restrict__ out) {
    int q = blockIdx.x * blockDim.x + threadIdx.x;
    if (q >= 3 * 4 * 256 * 4) return;
    int l = q >> 12;
    int rem = q & 4095;
    int kb = rem >> 10;
    int r  = (rem >> 2) & 255;
    int cc = rem & 3;
    int k0 = kb * 32 + (cc ^ ((r >> 1) & 3)) * 8;
    half8 v;
    #pragma unroll
    for (int e = 0; e < 8; e++) {
        int k = k0 + e;
        float f = (r < 128) ? Wn[l * 16384 + k * 128 + r]
                            : Ws[l * 16384 + k * 128 + (r - 128)];
        v[e] = (_Float16)f;
    }
    *(half8*)&out[(size_t)q * 8] = v;
}

// ----------------- layer-0 N-split GEMM: fp32 A staged raw, cvt at frag read
// block bx: M-tile = bx>>1 (128 rows), half nh = bx&1 (0: Cn fp16, 1: Cs+bias)
// LDS/buf: A 128x32 fp32 (16KB) + B-half 128x32 fp16 (8KB) = 24KB; dbuf 48KB
// -> 3 blocks/CU (vs 2 at 64KB in R5 — occupancy was the R5 limiter).
__global__ __launch_bounds__(256) void gemm0_ns(
    const float* __restrict__ A, int M, int K,
    const _Float16* __restrict__ Wtp, const float* __restrict__ bias,
    const float* __restrict__ zbuf,
    _Float16* __restrict__ Cn, float* __restrict__ Cs) {
    __shared__ char sbuf[2][24576];

    int tid = threadIdx.x;
    int wave = tid >> 6, lane = tid & 63;
    int lm = lane & 15, quad = lane >> 4;
    int wm = wave >> 1, wn = wave & 1;      // 2x2 waves: 64 rows x 64 cols each
    int bx = blockIdx.x;
    long row0 = (long)(bx >> 1) * 128;
    int nh = bx & 1;

    floatx4 acc[4][4] = {};

    auto stage = [&](int kb, char* buf) {
        // A: 1024 16B chunks (4 floats), XOR-swizzled slot cc holds chunk cc^(r&7)
        #pragma unroll
        for (int pass = 0; pass < 4; pass++) {
            int q = pass * 256 + tid;
            int r = q >> 3, cc = q & 7;
            int ccg = cc ^ (r & 7);
            long grow = row0 + r;
            int gk = kb * 32 + ccg * 4;
            const float* src = (gk + 4 <= K) ? (A + grow * (long)K + gk) : zbuf;
            char* dst = buf + pass * 4096 + wave * 1024;
            if (grow < M) cp16(src, dst);
        }
        // B half: 512 chunks, linear (pre-swizzled at pack time)
        const _Float16* wsrc = Wtp + (size_t)kb * 8192 + nh * 4096;
        #pragma unroll
        for (int pass = 0; pass < 2; pass++) {
            cp16(wsrc + (size_t)(pass * 256 + tid) * 8,
                 buf + 16384 + pass * 4096 + wave * 1024);
        }
    };

    stage(0, sbuf[0]);
    __syncthreads();

    for (int kb = 0; kb < NKB0; kb++) {
        int p = kb & 1;
        if (kb + 1 < NKB0) stage(kb + 1, sbuf[p ^ 1]);

        const float* Af = (const float*)sbuf[p];
        const _Float16* Bf = (const _Float16*)(sbuf[p] + 16384);
        half8 af[4];
        #pragma unroll
        for (int i = 0; i < 4; i++) {
            int row = wm * 64 + i * 16 + lm;
            int c0 = (quad * 2) ^ (row & 7);
            int c1 = (quad * 2 + 1) ^ (row & 7);
            floatx4 f0 = *(const floatx4*)&Af[row * 32 + c0 * 4];
            floatx4 f1 = *(const floatx4*)&Af[row * 32 + c1 * 4];
            af[i][0] = (_Float16)f0[0]; af[i][1] = (_Float16)f0[1];
            af[i][2] = (_Float16)f0[2]; af[i][3] = (_Float16)f0[3];
            af[i][4] = (_Float16)f1[0]; af[i][5] = (_Float16)f1[1];
            af[i][6] = (_Float16)f1[2]; af[i][7] = (_Float16)f1[3];
        }
        #pragma unroll
        for (int j = 0; j < 4; j++) {
            int brow = wn * 64 + j * 16 + lm;           // local row in the half
            int ch = quad ^ ((brow >> 1) & 3);          // (r>>1)&3 invariant mod 128
            half8 bf = *(const half8*)&Bf[brow * 32 + ch * 8];
            #pragma unroll
            for (int i = 0; i < 4; i++)
                acc[i][j] = __builtin_amdgcn_mfma_f32_16x16x32_f16(af[i], bf, acc[i][j], 0, 0, 0);
        }
        __syncthreads();
    }

    #pragma unroll
    for (int i = 0; i < 4; i++) {
        long r0 = row0 + wm * 64 + i * 16 + quad * 4;
        #pragma unroll
        for (int j = 0; j < 4; j++) {
            int c = wn * 64 + j * 16 + lm;              // output channel 0..127
            if (nh) {
                float badd = bias[c];
                #pragma unroll
                for (int rr = 0; rr < 4; rr++) {
                    long r = r0 + rr;
                    if (r < M) Cs[r * HDIM + c] = acc[i][j][rr] + badd;
                }
            } else {
                #pragma unroll
                for (int rr = 0; rr < 4; rr++) {
                    long r = r0 + rr;
                    if (r < M) Cn[r * HDIM + c] = (_Float16)acc[i][j][rr];
                }
            }
        }
    }
}

// -------------------- K=128 N-split GEMM: fp16 A; LDS 2x16KB -> 5 blocks/CU
__global__ __launch_bounds__(256) void gemm16_ns(
    const _Float16* __restrict__ A, int M,
    const _Float16* __restrict__ Wtp, const float* __restrict__ bias,
    _Float16* __restrict__ Cn, float* __restrict__ Cs) {
    __shared__ _Float16 sbuf[2][8192];   // A 4096 halves + B 4096 halves

    int tid = threadIdx.x;
    int wave = tid >> 6, lane = tid & 63;
    int lm = lane & 15, quad = lane >> 4;
    int wm = wave >> 1, wn = wave & 1;
    int bx = blockIdx.x;
    long row0 = (long)(bx >> 1) * 128;
    int nh = bx & 1;

    floatx4 acc[4][4] = {};

    auto stage = [&](int kb, _Float16* buf) {
        #pragma unroll
        for (int pass = 0; pass < 2; pass++) {
            int q = pass * 256 + tid;
            int r = q >> 2, cc = q & 3;
            int ccg = cc ^ ((r >> 1) & 3);
            long grow = row0 + r;
            _Float16* dst = buf + pass * 2048 + wave * 512;
            if (grow < M)
                cp16(A + grow * (long)HDIM + kb * 32 + ccg * 8, dst);
        }
        const _Float16* wsrc = Wtp + (size_t)kb * 8192 + nh * 4096;
        #pragma unroll
        for (int pass = 0; pass < 2; pass++) {
            cp16(wsrc + (size_t)(pass * 256 + tid) * 8,
                 buf + 4096 + pass * 2048 + wave * 512);
        }
    };

    stage(0, sbuf[0]);
    __syncthreads();

    for (int kb = 0; kb < 4; kb++) {
        int p = kb & 1;
        if (kb + 1 < 4) stage(kb + 1, sbuf[p ^ 1]);

        const _Float16* bp = sbuf[p];
        half8 af[4];
        #pragma unroll
        for (int i = 0; i < 4; i++) {
            int row = wm * 64 + i * 16 + lm;
            int ch = quad ^ ((row >> 1) & 3);
            af[i] = *(const half8*)&bp[row * 32 + ch * 8];
        }
        #pragma unroll
        for (int j = 0; j < 4; j++) {
            int brow = wn * 64 + j * 16 + lm;
            int ch = quad ^ ((brow >> 1) & 3);
            half8 bf = *(const half8*)&bp[4096 + brow * 32 + ch * 8];
            #pragma unroll
            for (int i = 0; i < 4; i++)
                acc[i][j] = __builtin_amdgcn_mfma_f32_16x16x32_f16(af[i], bf, acc[i][j], 0, 0, 0);
        }
        __syncthreads();
    }

    #pragma unroll
    for (int i = 0; i < 4; i++) {
        long r0 = row0 + wm * 64 + i * 16 + quad * 4;
        #pragma unroll
        for (int j = 0; j < 4; j++) {
            int c = wn * 64 + j * 16 + lm;
            if (nh) {
                float badd = bias[c];
                #pragma unroll
                for (int rr = 0; rr < 4; rr++) {
                    long r = r0 + rr;
                    if (r < M) Cs[r * HDIM + c] = acc[i][j][rr] + badd;
                }
            } else {
                #pragma unroll
                for (int rr = 0; rr < 4; rr++) {
                    long r = r0 + rr;
                    if (r < M) Cn[r * HDIM + c] = (_Float16)acc[i][j][rr];
                }
            }
        }
    }
}

// ------------------------------------------------------------- aggregation
__global__ __launch_bounds__(256) void aggregate_w(
    const _Float16* __restrict__ hn, const int* __restrict__ row_ptr,
    const int* __restrict__ esrc, float* __restrict__ pre) {
    int wave = threadIdx.x >> 6, lane = threadIdx.x & 63;
    int n = blockIdx.x * 4 + wave;
    if (n >= N_NODES) return;
    int start = row_ptr[n], end = row_ptr[n + 1];
    int eg = lane >> 4;            // edge slot 0..3
    int c8 = (lane & 15) * 8;      // channel group

    float acc[8] = {};
    for (int base = start; base < end; base += 16) {
        #pragma unroll
        for (int u = 0; u < 4; u++) {
            int e = base + u * 4 + eg;
            if (e < end) {
                int s = esrc[e];
                half8 v = *(const half8*)&hn[(size_t)s * HDIM + c8];
                #pragma unroll
                for (int i = 0; i < 8; i++) acc[i] += (float)v[i];
            }
        }
    }
    #pragma unroll
    for (int i = 0; i < 8; i++) {
        acc[i] += __shfl_xor(acc[i], 16, 64);
        acc[i] += __shfl_xor(acc[i], 32, 64);
    }
    if (eg == 0) {
        float rd = 1.0f / (float)max(end - start, 1);
        size_t off = (size_t)n * HDIM + c8;
        float4 p0 = *(float4*)&pre[off];
        float4 p1 = *(float4*)&pre[off + 4];
        p0.x += acc[0] * rd; p0.y += acc[1] * rd;
        p0.z += acc[2] * rd; p0.w += acc[3] * rd;
        p1.x += acc[4] * rd; p1.y += acc[5] * rd;
        p1.z += acc[6] * rd; p1.w += acc[7] * rd;
        *(float4*)&pre[off]     = p0;
        *(float4*)&pre[off + 4] = p1;
    }
}

// --------------------------------------------------------------- batch norm
__global__ void bn_stats(const float* __restrict__ P, float* __restrict__ gsum,
                         float* __restrict__ gsumsq, int M, int C) {
    int tid = threadIdx.x;
    int c = tid % C;
    int rpb = 256 / C;
    float s = 0.0f, s2 = 0.0f;
    for (int r = blockIdx.x * rpb + tid / C; r < M; r += gridDim.x * rpb) {
        float v = P[(size_t)r * C + c];
        s += v; s2 += v * v;
    }
    __shared__ float ss[256], ss2[256];
    ss[tid] = s; ss2[tid] = s2;
    __syncthreads();
    for (int off = 128; off >= C; off >>= 1) {
        if (tid < off) { ss[tid] += ss[tid + off]; ss2[tid] += ss2[tid + off]; }
        __syncthreads();
    }
    if (tid < C) {
        atomicAdd(&gsum[tid], ss[tid]);
        atomicAdd(&gsumsq[tid], ss2[tid]);
    }
}

// h16 = fp16(relu(P*scale+shift [+ res16])), scale/shift derived per-block
__global__ void bn_apply16(const float* __restrict__ P, const _Float16* __restrict__ res16,
                           _Float16* __restrict__ out16,
                           const float* __restrict__ gsum, const float* __restrict__ gsumsq,
                           const float* __restrict__ gamma, const float* __restrict__ beta,
                           int M, int total4, int Cdiv4) {
    __shared__ float ssc[HDIM], ssh[HDIM];
    int tid = threadIdx.x;
    int C = Cdiv4 * 4;
    if (tid < C) {
        float mean = gsum[tid] / (float)M;
        float var = gsumsq[tid] / (float)M - mean * mean;
        float sc = rsqrtf(var + 1e-5f) * gamma[tid];
        ssc[tid] = sc;
        ssh[tid] = beta[tid] - mean * sc;
    }
    __syncthreads();
    for (int f = blockIdx.x * blockDim.x + tid; f < total4;
         f += gridDim.x * blockDim.x) {
        int c4 = (f % Cdiv4) * 4;
        float4 v = ((const float4*)P)[f];
        v.x = v.x * ssc[c4 + 0] + ssh[c4 + 0];
        v.y = v.y * ssc[c4 + 1] + ssh[c4 + 1];
        v.z = v.z * ssc[c4 + 2] + ssh[c4 + 2];
        v.w = v.w * ssc[c4 + 3] + ssh[c4 + 3];
        if (res16) {
            half4 rv = *(const half4*)&res16[(size_t)f * 4];
            v.x += (float)rv[0]; v.y += (float)rv[1];
            v.z += (float)rv[2]; v.w += (float)rv[3];
        }
        half4 h;
        h[0] = (_Float16)fmaxf(v.x, 0.0f); h[1] = (_Float16)fmaxf(v.y, 0.0f);
        h[2] = (_Float16)fmaxf(v.z, 0.0f); h[3] = (_Float16)fmaxf(v.w, 0.0f);
        *(half4*)&out16[(size_t)f * 4] = h;
    }
}

// --------------------------------------------------------------- MLP head
__global__ __launch_bounds__(256) void mlp_gemm(const _Float16* __restrict__ H,
                                                const float* __restrict__ W1,
                                                const float* __restrict__ b1,
                                                float* __restrict__ Z, int M) {
    __shared__ float hs[64 * 132];
    __shared__ float ws[128 * 64];
    int tid = threadIdx.x;
    int tx = tid & 15;
    int ty = tid >> 4;
    int row0 = blockIdx.x * 64;

    #pragma unroll
    for (int t = 0; t < 8; t++) {
        int f = tid + t * 256;
        int r = f >> 4, c4 = (f & 15) * 4;
        *(float4*)&ws[r * 64 + c4] = *(const float4*)&W1[r * 64 + c4];
    }
    #pragma unroll
    for (int t = 0; t < 4; t++) {
        int f = tid + t * 256;
        int r = f >> 4, c8 = (f & 15) * 8;
        int gr = row0 + r;
        if (gr < M) {
            half8 hv = *(const half8*)&H[(size_t)gr * HDIM + c8];
            #pragma unroll
            for (int i = 0; i < 8; i++) hs[r * 132 + c8 + i] = (float)hv[i];
        } else {
            #pragma unroll
            for (int i = 0; i < 8; i++) hs[r * 132 + c8 + i] = 0.0f;
        }
    }
    __syncthreads();

    float acc[4][4] = {};
    for (int k = 0; k < 128; k++) {
        float a[4];
        #pragma unroll
        for (int i = 0; i < 4; i++) a[i] = hs[(ty * 4 + i) * 132 + k];
        float4 b4 = *(const float4*)&ws[k * 64 + tx * 4];
        #pragma unroll
        for (int i = 0; i < 4; i++) {
            acc[i][0] += a[i] * b4.x; acc[i][1] += a[i] * b4.y;
            acc[i][2] += a[i] * b4.z; acc[i][3] += a[i] * b4.w;
        }
    }
    float4 bb = *(const float4*)&b1[tx * 4];
    #pragma unroll
    for (int i = 0; i < 4; i++) {
        int r = row0 + ty * 4 + i;
        if (r < M) {
            float4 v = {acc[i][0] + bb.x, acc[i][1] + bb.y,
                        acc[i][2] + bb.z, acc[i][3] + bb.w};
            *(float4*)&Z[(size_t)r * 64 + tx * 4] = v;
        }
    }
}

// out[n] = relu(bn(Z[n,:])) . W2 + b2  — BN finalize+apply fused into the dot
__global__ void final_out(const float* __restrict__ Z,
                          const float* __restrict__ gsum, const float* __restrict__ gsumsq,
                          const float* __restrict__ gamma, const float* __restrict__ beta,
                          const float* __restrict__ W2, const float* __restrict__ b2,
                          float* __restrict__ out, int M) {
    __shared__ float ssc[64], ssh[64], sw[64];
    int tid = threadIdx.x;
    if (tid < 64) {
        float mean = gsum[tid] / (float)M;
        float var = gsumsq[tid] / (float)M - mean * mean;
        float sc = rsqrtf(var + 1e-5f) * gamma[tid];
        ssc[tid] = sc;
        ssh[tid] = beta[tid] - mean * sc;
        sw[tid] = W2[tid];
    }
    __syncthreads();
    int n = blockIdx.x * 4 + (tid >> 6);
    int lane = tid & 63;
    if (n >= N_NODES) return;
    float z = Z[(size_t)n * 64 + lane] * ssc[lane] + ssh[lane];
    z = fmaxf(z, 0.0f);
    float v = z * sw[lane];
    #pragma unroll
    for (int off = 32; off >= 1; off >>= 1) v += __shfl_down(v, off, 64);
    if (lane == 0) out[n] = v + b2[0];
}

// ------------------------------------------------------------------ driver
extern "C" void kernel_launch(void* const* d_in, const int* in_sizes, int n_in,
                              void* d_out, int out_size, void* d_ws, size_t ws_size,
                              hipStream_t stream) {
    const float* X       = (const float*)d_in[0];
    const int*   graph   = (const int*)d_in[1];
    const float* Wself0  = (const float*)d_in[2];
    const float* Wneigh0 = (const float*)d_in[3];
    const float* b0      = (const float*)d_in[4];
    const float* Wself   = (const float*)d_in[5];
    const float* Wneigh  = (const float*)d_in[6];
    const float* bvec    = (const float*)d_in[7];
    const float* bn_g    = (const float*)d_in[8];
    const float* bn_b    = (const float*)d_in[9];
    const float* W1      = (const float*)d_in[10];
    const float* b1      = (const float*)d_in[11];
    const float* bng1    = (const float*)d_in[12];
    const float* bnb1    = (const float*)d_in[13];
    const float* W2      = (const float*)d_in[14];
    const float* b2      = (const float*)d_in[15];
    float* out = (float*)d_out;

    size_t off = 0;
    auto alloc = [&](size_t bytes) {
        void* p = (char*)d_ws + off;
        off += (bytes + 255) & ~(size_t)255;
        return p;
    };
    int* cnt     = (int*)alloc(N_NODES * 4);
    int* cursor  = (int*)alloc(N_NODES * 4);
    int* row_ptr = (int*)alloc((N_NODES + 1) * 4);
    int* incl    = (int*)alloc(N_NODES * 4);
    int* blk     = (int*)alloc(NB_SCAN * 4);
    int* blkoff  = (int*)alloc(NB_SCAN * 4);
    int* esrc    = (int*)alloc((size_t)N_EDGES * 4);
    float*    pre   = (float*)alloc((size_t)N_NODES * HDIM * 4);    // 51.2 MB
    _Float16* h16A  = (_Float16*)alloc((size_t)N_NODES * HDIM * 2); // 25.6 MB
    _Float16* h16B  = (_Float16*)alloc((size_t)N_NODES * HDIM * 2);
    _Float16* hn16  = (_Float16*)alloc((size_t)N_NODES * HDIM * 2);
    float*    Z     = (float*)alloc((size_t)N_NODES * 64 * 4);
    _Float16* Wtp0  = (_Float16*)alloc((size_t)NKB0 * 8192 * 2);
    _Float16* Wtpl  = (_Float16*)alloc((size_t)3 * 4 * 8192 * 2);
    float*    zbuf  = (float*)alloc(256);
    float* stats = (float*)alloc(256 * 4);
    float* gsum = stats, *gsumsq = stats + 128;

    const int EB = (N_EDGES + 255) / 256;
    const int GB = ((N_NODES + 127) / 128) * 2;   // 1564 (M-tiles x 2 N-halves)
    const int AGB = (N_NODES + 3) / 4;            // 25000

    // CSR build
    hipMemsetAsync(cnt, 0, N_NODES * 4, stream);
    hipMemsetAsync(cursor, 0, N_NODES * 4, stream);
    hipMemsetAsync(zbuf, 0, 256, stream);
    count_edges<<<EB, 256, 0, stream>>>(graph, cnt);
    scan1<<<NB_SCAN, SCAN_B, 0, stream>>>(cnt, incl, blk);
    scan2<<<1, 512, 0, stream>>>(blk, blkoff);
    scan3<<<NB_SCAN, SCAN_B, 0, stream>>>(incl, blkoff, row_ptr);
    fill_edges<<<EB, 256, 0, stream>>>(graph, row_ptr, cursor, esrc);

    // weight packs
    build_wtp0<<<(NKB0 * 1024 + 255) / 256, 256, 0, stream>>>(Wneigh0, Wself0, Wtp0);
    build_wtpl<<<(3 * 4096 + 255) / 256, 256, 0, stream>>>(Wneigh, Wself, Wtpl);

    _Float16* hc = h16A;
    _Float16* hx = h16B;

    // ---- layer 0 (K = 700, fp32 A direct, N-split)
    gemm0_ns<<<GB, 256, 0, stream>>>(X, N_NODES, F_IN, Wtp0, b0, zbuf, hn16, pre);
    aggregate_w<<<AGB, 256, 0, stream>>>(hn16, row_ptr, esrc, pre);
    hipMemsetAsync(stats, 0, 256 * 4, stream);
    bn_stats<<<512, 256, 0, stream>>>(pre, gsum, gsumsq, N_NODES, 128);
    bn_apply16<<<1024, 256, 0, stream>>>(pre, nullptr, hc, gsum, gsumsq,
                                         bn_g, bn_b, N_NODES,
                                         N_NODES * HDIM / 4, HDIM / 4);

    // ---- layers 1..3 (K = 128, residual in fp16, N-split)
    for (int l = 0; l < 3; l++) {
        gemm16_ns<<<GB, 256, 0, stream>>>(hc, N_NODES, Wtpl + (size_t)l * 32768,
                                          bvec + l * HDIM, hn16, pre);
        aggregate_w<<<AGB, 256, 0, stream>>>(hn16, row_ptr, esrc, pre);
        hipMemsetAsync(stats, 0, 256 * 4, stream);
        bn_stats<<<512, 256, 0, stream>>>(pre, gsum, gsumsq, N_NODES, 128);
        bn_apply16<<<1024, 256, 0, stream>>>(pre, hc, hx, gsum, gsumsq,
                                             bn_g + (l + 1) * HDIM,
                                             bn_b + (l + 1) * HDIM, N_NODES,
                                             N_NODES * HDIM / 4, HDIM / 4);
        _Float16* t = hc; hc = hx; hx = t;
    }

    // ---- MLP head (BN finalize+apply+ReLU fused into final_out)
    mlp_gemm<<<(N_NODES + 63) / 64, 256, 0, stream>>>(hc, W1, b1, Z, N_NODES);
    hipMemsetAsync(stats, 0, 256 * 4, stream);
    bn_stats<<<512, 256, 0, stream>>>(Z, gsum, gsumsq, N_NODES, 64);
    final_out<<<AGB, 256, 0, stream>>>(Z, gsum, gsumsq, bng1, bnb1, W2, b2,
                                       out, N_NODES);
}